// Round 9
// baseline (217.526 us; speedup 1.0000x reference)
//
#include <hip/hip_runtime.h>
#include <hip/hip_bf16.h>

typedef __attribute__((ext_vector_type(8))) short short8;
typedef __attribute__((ext_vector_type(4))) float f32x4;

static constexpr int B_ = 64;
static constexpr int N_ = 4096;
static constexpr int V_ = 21;
static constexpr int S_ = 50;
static constexpr int E_ = 64;
static constexpr int H_ = 128;
static constexpr int NPAIR = V_ * V_;   // 441
static constexpr int NTAB = NPAIR * S_; // 22050

__device__ __forceinline__ float rcp_(float x) { return __builtin_amdgcn_rcpf(x); }
__device__ __forceinline__ float sigm(float x) { return rcp_(1.0f + __expf(-x)); }
__device__ __forceinline__ float tanh_(float x) {
  float a = fabsf(x);
  float e = __expf(-2.0f * a);
  float t = (1.0f - e) * rcp_(1.0f + e);
  return x < 0.0f ? -t : t;
}
__device__ __forceinline__ unsigned short f2bf(float f) {
  __hip_bfloat16 b = __float2bfloat16(f);
  return *reinterpret_cast<unsigned short*>(&b);
}
__device__ __forceinline__ float bf2f(unsigned short u) {
  return __uint_as_float(((unsigned int)u) << 16);
}

struct Gates { float cv, hv; };
__device__ __forceinline__ Gates gate_combine(float4 sx,
    float i_p, float o_p, float u_p, float fl_p, float fr_p, float cl, float cr) {
  float gi = sigm(sx.x + i_p);
  float go = sigm(sx.y + o_p);
  float gu = tanh_(sx.z + u_p);
  float fl = sigm(sx.w + fl_p);
  float fr = sigm(sx.w + fr_p);
  float cv = fmaf(gi, gu, fmaf(fl, cl, fr * cr));
  Gates g; g.cv = cv; g.hv = go * tanh_(cv);
  return g;
}

// Raw barriers (no vmcnt drain): global prefetches stay in flight across them.
__device__ __forceinline__ void bar_lds() {
  asm volatile("s_waitcnt lgkmcnt(0)" ::: "memory");
  __builtin_amdgcn_s_barrier();
  asm volatile("" ::: "memory");
}
__device__ __forceinline__ void bar_only() {
  asm volatile("" ::: "memory");
  __builtin_amdgcn_s_barrier();
  asm volatile("" ::: "memory");
}

// ---- k_pre: Wfrag build + leaf tables + symx + idx1, all in one launch ----
__global__ void __launch_bounds__(512) k_pre(
    const float* __restrict__ Ui, const float* __restrict__ Uo,
    const float* __restrict__ Uu, const float* __restrict__ Uf,
    const float* __restrict__ Wi, const float* __restrict__ Wo,
    const float* __restrict__ Wu, const float* __restrict__ Wf,
    const float* __restrict__ Wp, const float* __restrict__ emb,
    const float* __restrict__ sym_emb,
    const float* __restrict__ bp, const float* __restrict__ bi,
    const float* __restrict__ bo, const float* __restrict__ bu,
    const float* __restrict__ bfv,
    const int* __restrict__ tokens, const int* __restrict__ symbols,
    unsigned short* __restrict__ Wfrag, float* __restrict__ leaf_c,
    float* __restrict__ symx, float* __restrict__ P_leaf,
    int* __restrict__ idx1) {
  __shared__ float x[128];
  __shared__ float zs[512];
  __shared__ float hl[128];
  int blk = blockIdx.x, t = threadIdx.x;
  if (blk < 16) {
    int idx = blk * 512 + t;  // 8192 frag entries
    int L = idx & 63;
    int K = (idx >> 6) & 3;
    int T = idx >> 8;
    int n = 16 * T + (L & 15);
    int k0 = 32 * K + ((L >> 4) << 3);
    int g = n >> 7, o = n & 127;
    const float* U = (g == 0) ? Ui : (g == 1) ? Uo : (g == 2) ? Uu : Uf;
    unsigned short out[8];
    #pragma unroll
    for (int j = 0; j < 8; ++j) out[j] = f2bf(U[o * 128 + k0 + j]);
    *(int4*)(Wfrag + (size_t)idx * 8) = *(int4*)out;
  } else if (blk < 16 + V_) {
    int v = blk - 16;
    if (t < 128) {
      float acc = bp[t];
      if (v != 0) {  // reference zeroes emb row 0
        const float4* wr = (const float4*)(Wp + t * E_);
        const float4* er = (const float4*)(emb + v * E_);
        #pragma unroll 4
        for (int e4 = 0; e4 < E_ / 4; ++e4) {
          float4 w4 = wr[e4], e4v = er[e4];
          acc = fmaf(e4v.x, w4.x, acc); acc = fmaf(e4v.y, w4.y, acc);
          acc = fmaf(e4v.z, w4.z, acc); acc = fmaf(e4v.w, w4.w, acc);
        }
      }
      x[t] = acc;
    }
    __syncthreads();
    if (t < 384) {  // cols 0..383 = i|o|u
      int g = t >> 7, o = t & 127;
      const float* bb = (g == 0) ? bi : (g == 1) ? bo : bu;
      const float* Wg = (g == 0) ? Wi : (g == 1) ? Wo : Wu;
      float z = bb[o];
      const float4* wr = (const float4*)(Wg + o * H_);
      #pragma unroll 4
      for (int k4 = 0; k4 < H_ / 4; ++k4) {
        float4 w4 = wr[k4];
        z = fmaf(x[4 * k4], w4.x, z); z = fmaf(x[4 * k4 + 1], w4.y, z);
        z = fmaf(x[4 * k4 + 2], w4.z, z); z = fmaf(x[4 * k4 + 3], w4.w, z);
      }
      zs[t] = z;
    }
    __syncthreads();
    if (t < 128) {
      float gi = sigm(zs[t]), go = sigm(zs[128 + t]), gu = tanh_(zs[256 + t]);
      float c = gi * gu;
      leaf_c[v * H_ + t] = c;
      unsigned short hb = f2bf(go * tanh_(c));
      hl[t] = bf2f(hb);
    }
    __syncthreads();
    {  // P_leaf row v: bf16-rounded h x fp32 U, all 512 cols (order i|o|u|f)
      int g = t >> 7, o = t & 127;
      const float* Ug = (g == 0) ? Ui : (g == 1) ? Uo : (g == 2) ? Uu : Uf;
      float z = 0.f;
      const float4* wr = (const float4*)(Ug + o * H_);
      #pragma unroll 4
      for (int k4 = 0; k4 < H_ / 4; ++k4) {
        float4 w4 = wr[k4];
        z = fmaf(hl[4 * k4], w4.x, z); z = fmaf(hl[4 * k4 + 1], w4.y, z);
        z = fmaf(hl[4 * k4 + 2], w4.z, z); z = fmaf(hl[4 * k4 + 3], w4.w, z);
      }
      P_leaf[(size_t)v * 512 + t] = z;
    }
  } else if (blk < 16 + V_ + S_) {
    int s = blk - 16 - V_;
    if (t < 128) {
      float acc = bp[t];
      const float4* wr = (const float4*)(Wp + t * E_);
      const float4* er = (const float4*)(sym_emb + s * E_);
      #pragma unroll 4
      for (int e4 = 0; e4 < E_ / 4; ++e4) {
        float4 w4 = wr[e4], e4v = er[e4];
        acc = fmaf(e4v.x, w4.x, acc); acc = fmaf(e4v.y, w4.y, acc);
        acc = fmaf(e4v.z, w4.z, acc); acc = fmaf(e4v.w, w4.w, acc);
      }
      x[t] = acc;
    }
    __syncthreads();
    {
      int g = t >> 7, o = t & 127;
      const float* bb = (g == 0) ? bi : (g == 1) ? bo : (g == 2) ? bu : bfv;
      const float* Wg = (g == 0) ? Wi : (g == 1) ? Wo : (g == 2) ? Wu : Wf;
      float z = bb[o];
      const float4* wr = (const float4*)(Wg + o * H_);
      #pragma unroll 4
      for (int k4 = 0; k4 < H_ / 4; ++k4) {
        float4 w4 = wr[k4];
        z = fmaf(x[4 * k4], w4.x, z); z = fmaf(x[4 * k4 + 1], w4.y, z);
        z = fmaf(x[4 * k4 + 2], w4.z, z); z = fmaf(x[4 * k4 + 3], w4.w, z);
      }
      zs[t] = z;
    }
    __syncthreads();
    if (t < 128) {
      float4 v4 = make_float4(zs[t], zs[128 + t], zs[256 + t], zs[384 + t]);
      *(float4*)(symx + (size_t)s * 512 + t * 4) = v4;
    }
  } else {
    int g = (blk - 16 - V_ - S_) * 512 + t;   // 131072 level-1 nodes
    int b = g >> 11, j = g & 2047;
    idx1[g] = (tokens[b * N_ + 2 * j] * V_ + tokens[b * N_ + 2 * j + 1]) * S_
              + symbols[b * (N_ - 1) + j];
  }
}

// ---- tabB: gate epilogue over 22050 rows (gathering from P_leaf) ----
__global__ void k_tabB(const float* __restrict__ P_leaf, const float* __restrict__ symx,
                       const float* __restrict__ leaf_c,
                       unsigned short* __restrict__ tab_h8, float* __restrict__ tab_c) {
  int blk = blockIdx.x, t = threadIdx.x;
  int row = blk * 2 + (t >> 7);
  int u = t & 127;
  int p = row / S_, s = row - p * S_;
  int tl = p / V_, tr = p - tl * V_;
  const float* Pl = P_leaf + (size_t)tl * 512;
  const float* Pr = P_leaf + (size_t)tr * 512;
  float4 sx = *(const float4*)(symx + (size_t)s * 512 + u * 4);
  Gates gt = gate_combine(sx,
      Pl[u] + Pr[u], Pl[128 + u] + Pr[128 + u], Pl[256 + u] + Pr[256 + u],
      Pl[384 + u], Pr[384 + u],
      leaf_c[tl * H_ + u], leaf_c[tr * H_ + u]);
  tab_c[(size_t)row * H_ + u] = gt.cv;
  tab_h8[(size_t)row * H_ + u] = f2bf(gt.hv);
}

// ---- fused levels 2+3: PERSISTENT blocks (grid 512 x CH 8), pipelined h-row
// gather, hoisted weights, raw barriers. REGISTER DIET vs r8: no index-prefetch
// rotation, phase-1 serialized over the two A-row halves (acc[4] reused).
// Target: <=128 unified VGPR+AGPR per wave -> 2 blocks/CU resident.
__global__ void __launch_bounds__(512) k_lvl23(
    const unsigned short* __restrict__ Wfrag, const float* __restrict__ symx,
    const int* __restrict__ symbols, const int* __restrict__ idx1,
    const unsigned short* __restrict__ gh8, const float* __restrict__ gc,
    unsigned short* __restrict__ h_out8, float* __restrict__ c_out) {
  __shared__ __align__(16) unsigned short Ag[32][136];
  __shared__ __align__(16) unsigned short Bh[16][136];
  __shared__ float Bc[16][132];
  const int t = threadIdx.x;
  const int w = t >> 6, L = t & 63, q = L >> 4, cL = L & 15;
  const int cc = 16 * w + cL;
  const int rowA = t >> 4, coA = (t & 15) * 8;

  // hoist weight fragments once per block (16 short8 = 64 regs)
  const short8* wf = (const short8*)Wfrag;
  short8 bfr[4][4];
  #pragma unroll
  for (int K = 0; K < 4; ++K)
    #pragma unroll
    for (int g = 0; g < 4; ++g)
      bfr[g][K] = wf[(size_t)((w + 8 * g) * 4 + K) * 64 + L];

  const int CH = 8;                   // tiles per block; grid = 512
  const int t0 = blockIdx.x * CH;

  int nn[4];
  #pragma unroll
  for (int it = 0; it < 4; ++it) nn[it] = 8 * (it >> 1) + 2 * q + (it & 1);

  // ---- prologue: h-row prefetch for tile t0 ----
  int4 agv;
  {
    int gxr = idx1[t0 * 32 + rowA];
    agv = *(const int4*)(gh8 + (size_t)gxr * H_ + coA);
  }

  for (int k = 0; k < CH; ++k) {
    const int tile = t0 + k;
    const int j2 = (tile & 63) * 16;
    const int* sb = symbols + (size_t)(tile >> 6) * (N_ - 1);
    const bool hasNext = (k + 1 < CH);

    bar_only();                       // prev phase-2 done with Bh/Bc; Ag free
    *(int4*)&Ag[rowA][coA] = agv;
    bar_lds();                        // Ag visible to all waves

    // this-tile index loads (L2-hot) + child-c gathers (L3)
    int g2l[4], g2r[4], sp1[4];
    #pragma unroll
    for (int it = 0; it < 4; ++it) {
      g2l[it] = idx1[tile * 32 + 2 * nn[it]];
      g2r[it] = idx1[tile * 32 + 2 * nn[it] + 1];
      sp1[it] = sb[2048 + j2 + nn[it]];
    }
    float clp[4], crp[4];
    #pragma unroll
    for (int it = 0; it < 4; ++it) {
      clp[it] = gc[(size_t)g2l[it] * H_ + cc];
      crp[it] = gc[(size_t)g2r[it] * H_ + cc];
    }
    int sp2[2];
    sp2[0] = sb[3072 + (j2 >> 1) + 2 * q];
    sp2[1] = sb[3072 + (j2 >> 1) + 2 * q + 1];
    int gxr_n = hasNext ? idx1[(tile + 1) * 32 + rowA] : 0;

    // ---- phase 1: 16 L2 nodes, serialized over the two A-row halves ----
    #pragma unroll
    for (int r = 0; r < 2; ++r) {
      f32x4 acc[4];
      #pragma unroll
      for (int g = 0; g < 4; ++g) acc[g] = (f32x4){0.f, 0.f, 0.f, 0.f};
      #pragma unroll
      for (int K = 0; K < 4; ++K) {
        short8 a = *(const short8*)&Ag[16 * r + cL][K * 32 + q * 8];
        #pragma unroll
        for (int g = 0; g < 4; ++g)
          acc[g] = __builtin_amdgcn_mfma_f32_16x16x32_bf16(a, bfr[g][K], acc[g], 0, 0, 0);
      }
      // issue next tile's h-row gather between the halves (long-latency)
      if (r == 0 && hasNext) agv = *(const int4*)(gh8 + (size_t)gxr_n * H_ + coA);
      #pragma unroll
      for (int nd = 0; nd < 2; ++nd) {
        int it = 2 * r + nd;
        int n = 8 * r + 2 * q + nd;
        float4 sx = *(const float4*)(symx + (size_t)sp1[it] * 512 + cc * 4);
        Gates gt = gate_combine(sx,
            acc[0][2 * nd] + acc[0][2 * nd + 1],
            acc[1][2 * nd] + acc[1][2 * nd + 1],
            acc[2][2 * nd] + acc[2][2 * nd + 1],
            acc[3][2 * nd], acc[3][2 * nd + 1], clp[it], crp[it]);
        Bc[n][cc] = gt.cv;
        Bh[n][cc] = f2bf(gt.hv);
      }
    }
    bar_lds();                        // Bh/Bc visible

    // ---- phase 2: 8 L3 nodes ----
    f32x4 acc2[4];
    #pragma unroll
    for (int g = 0; g < 4; ++g) acc2[g] = (f32x4){0.f, 0.f, 0.f, 0.f};
    #pragma unroll
    for (int K = 0; K < 4; ++K) {
      short8 a0 = *(const short8*)&Bh[cL][K * 32 + q * 8];
      #pragma unroll
      for (int g = 0; g < 4; ++g)
        acc2[g] = __builtin_amdgcn_mfma_f32_16x16x32_bf16(a0, bfr[g][K], acc2[g], 0, 0, 0);
    }
    #pragma unroll
    for (int nd = 0; nd < 2; ++nd) {
      int n = 2 * q + nd;
      int G3 = tile * 8 + n;
      float4 sx = *(const float4*)(symx + (size_t)sp2[nd] * 512 + cc * 4);
      Gates gt = gate_combine(sx,
          acc2[0][2 * nd] + acc2[0][2 * nd + 1],
          acc2[1][2 * nd] + acc2[1][2 * nd + 1],
          acc2[2][2 * nd] + acc2[2][2 * nd + 1],
          acc2[3][2 * nd], acc2[3][2 * nd + 1],
          Bc[2 * n][cc], Bc[2 * n + 1][cc]);
      c_out[(size_t)G3 * H_ + cc] = gt.cv;
      h_out8[(size_t)G3 * H_ + cc] = f2bf(gt.hv);
    }
  }
}

// ---- k_mid: levels 4-9 fused; 512 blocks, subtree-local, LDS ping-pong ----
// Weight fragments hoisted to registers once per block (budget 256 @ occ 2).
__global__ void __launch_bounds__(512, 2) k_mid(
    const unsigned short* __restrict__ Wfrag, const float* __restrict__ symx,
    const int* __restrict__ symbols,
    const unsigned short* __restrict__ in_h8, const float* __restrict__ in_c,
    unsigned short* __restrict__ out_h8, float* __restrict__ out_c) {
  __shared__ __align__(16) unsigned short Ah0[64][136];
  __shared__ __align__(16) unsigned short Ah1[32][136];
  __shared__ float Cs0[64][128];
  __shared__ float Cs1[32][128];
  int t = threadIdx.x;
  int w = t >> 6, L = t & 63, q = L >> 4, cL = L & 15;
  int cc = 16 * w + cL;
  int blk = blockIdx.x;
  int b = blk >> 3, sub = blk & 7;
  size_t base3 = (size_t)blk * 64;

  const short8* wf = (const short8*)Wfrag;
  short8 bfr[4][4];
  #pragma unroll
  for (int K = 0; K < 4; ++K)
    #pragma unroll
    for (int g = 0; g < 4; ++g)
      bfr[g][K] = wf[(size_t)((w + 8 * g) * 4 + K) * 64 + L];

  #pragma unroll
  for (int i = 0; i < 2; ++i) {
    int fid = t + 512 * i;
    int row = fid >> 4, co = (fid & 15) * 8;
    *(int4*)&Ah0[row][co] = *(const int4*)(in_h8 + (base3 + row) * H_ + co);
  }
  #pragma unroll
  for (int i = 0; i < 4; ++i) {
    int fid = t + 512 * i;
    int row = fid >> 5, c4 = (fid & 31) << 2;
    *(float4*)&Cs0[row][c4] = *(const float4*)(in_c + (base3 + row) * H_ + c4);
  }
  __syncthreads();

  int R = 64;
  #pragma unroll
  for (int lev = 0; lev < 6; ++lev) {
    const int l = 4 + lev;
    const int nodes = R >> 1;
    const int jb = b * (N_ - 1) + (N_ - (N_ >> (l - 1))) + ((sub * 32) >> lev);
    unsigned short (*Ard)[136] = (lev & 1) ? Ah1 : Ah0;
    unsigned short (*Awr)[136] = (lev & 1) ? Ah0 : Ah1;
    const float* crd = (lev & 1) ? &Cs1[0][0] : &Cs0[0][0];
    float* cwr = (lev & 1) ? &Cs0[0][0] : &Cs1[0][0];
    const int nchunk = (nodes + 15) >> 4;
    for (int c = 0; c < nchunk; ++c) {
      int spre[4];
      #pragma unroll
      for (int it = 0; it < 4; ++it) {
        int n = 16 * c + 8 * (it >> 1) + 2 * q + (it & 1);
        spre[it] = (n < nodes) ? symbols[jb + n] : 0;
      }
      f32x4 acc[2][4];
      #pragma unroll
      for (int r = 0; r < 2; ++r)
        #pragma unroll
        for (int g = 0; g < 4; ++g) acc[r][g] = (f32x4){0.f, 0.f, 0.f, 0.f};
      const bool useA1 = (2 * nodes - 32 * c) > 16;
      #pragma unroll
      for (int K = 0; K < 4; ++K) {
        short8 a0 = *(const short8*)&Ard[32 * c + cL][K * 32 + q * 8];
        #pragma unroll
        for (int g = 0; g < 4; ++g)
          acc[0][g] = __builtin_amdgcn_mfma_f32_16x16x32_bf16(a0, bfr[g][K], acc[0][g], 0, 0, 0);
        if (useA1) {
          short8 a1 = *(const short8*)&Ard[32 * c + 16 + cL][K * 32 + q * 8];
          #pragma unroll
          for (int g = 0; g < 4; ++g)
            acc[1][g] = __builtin_amdgcn_mfma_f32_16x16x32_bf16(a1, bfr[g][K], acc[1][g], 0, 0, 0);
        }
      }
      #pragma unroll
      for (int r = 0; r < 2; ++r) {
        #pragma unroll
        for (int nd = 0; nd < 2; ++nd) {
          int it = r * 2 + nd;
          int n = 16 * c + 8 * r + 2 * q + nd;
          if (n < nodes) {
            float4 sx = *(const float4*)(symx + (size_t)spre[it] * 512 + cc * 4);
            Gates gt = gate_combine(sx,
                acc[r][0][2 * nd] + acc[r][0][2 * nd + 1],
                acc[r][1][2 * nd] + acc[r][1][2 * nd + 1],
                acc[r][2][2 * nd] + acc[r][2][2 * nd + 1],
                acc[r][3][2 * nd], acc[r][3][2 * nd + 1],
                crd[(size_t)(2 * n) * 128 + cc], crd[(size_t)(2 * n + 1) * 128 + cc]);
            if (lev == 5) {
              out_c[(size_t)blk * H_ + cc] = gt.cv;
              out_h8[(size_t)blk * H_ + cc] = f2bf(gt.hv);
            } else {
              cwr[(size_t)n * 128 + cc] = gt.cv;
              Awr[n][cc] = f2bf(gt.hv);
            }
          }
        }
      }
    }
    __syncthreads();
    R >>= 1;
  }
}

// ---- k_fin: levels 10-12 + fused projection (direct Wout rows); 64 blocks ----
__global__ void __launch_bounds__(512, 2) k_fin(
    const unsigned short* __restrict__ Wfrag, const float* __restrict__ symx,
    const int* __restrict__ symbols,
    const unsigned short* __restrict__ in_h8, const float* __restrict__ in_c,
    const float* __restrict__ Wout, const float* __restrict__ bout,
    float* __restrict__ out) {
  __shared__ __align__(16) unsigned short Ah0[8][136];
  __shared__ __align__(16) unsigned short Ah1[4][136];
  __shared__ float Cs0[8][128];
  __shared__ float Cs1[4][128];
  __shared__ float rootv[128];
  int t = threadIdx.x;
  int w = t >> 6, L = t & 63, q = L >> 4, cL = L & 15;
  int cc = 16 * w + cL;
  int b = blockIdx.x;

  const short8* wf = (const short8*)Wfrag;
  short8 bfr[4][4];
  #pragma unroll
  for (int K = 0; K < 4; ++K)
    #pragma unroll
    for (int g = 0; g < 4; ++g)
      bfr[g][K] = wf[(size_t)((w + 8 * g) * 4 + K) * 64 + L];

  if (t < 128) {
    int row = t >> 4, co = (t & 15) * 8;
    *(int4*)&Ah0[row][co] = *(const int4*)(in_h8 + (size_t)(b * 8 + row) * H_ + co);
  }
  if (t < 256) {
    int row = t >> 5, c4 = (t & 31) << 2;
    *(float4*)&Cs0[row][c4] = *(const float4*)(in_c + (size_t)(b * 8 + row) * H_ + c4);
  }
  __syncthreads();

  int R = 8;
  #pragma unroll
  for (int lev = 0; lev < 3; ++lev) {
    const int l = 10 + lev;
    const int nodes = R >> 1;
    const int jb = b * (N_ - 1) + (N_ - (N_ >> (l - 1)));
    unsigned short (*Ard)[136] = (lev & 1) ? Ah1 : Ah0;
    unsigned short (*Awr)[136] = (lev & 1) ? Ah0 : Ah1;
    const float* crd = (lev & 1) ? &Cs1[0][0] : &Cs0[0][0];
    float* cwr = (lev & 1) ? &Cs0[0][0] : &Cs1[0][0];
    int spre[4];
    #pragma unroll
    for (int it = 0; it < 4; ++it) {
      int n = 8 * (it >> 1) + 2 * q + (it & 1);
      spre[it] = (n < nodes) ? symbols[jb + n] : 0;
    }
    f32x4 acc[4];
    #pragma unroll
    for (int g = 0; g < 4; ++g) acc[g] = (f32x4){0.f, 0.f, 0.f, 0.f};
    #pragma unroll
    for (int K = 0; K < 4; ++K) {
      short8 a0 = *(const short8*)&Ard[cL & 7][K * 32 + q * 8];
      #pragma unroll
      for (int g = 0; g < 4; ++g)
        acc[g] = __builtin_amdgcn_mfma_f32_16x16x32_bf16(a0, bfr[g][K], acc[g], 0, 0, 0);
    }
    #pragma unroll
    for (int nd = 0; nd < 2; ++nd) {
      int it = nd;
      int n = 2 * q + nd;
      if (n < nodes) {
        float4 sx = *(const float4*)(symx + (size_t)spre[it] * 512 + cc * 4);
        Gates gt = gate_combine(sx,
            acc[0][2 * nd] + acc[0][2 * nd + 1],
            acc[1][2 * nd] + acc[1][2 * nd + 1],
            acc[2][2 * nd] + acc[2][2 * nd + 1],
            acc[3][2 * nd], acc[3][2 * nd + 1],
            crd[(size_t)(2 * n) * 128 + cc], crd[(size_t)(2 * n + 1) * 128 + cc]);
        if (lev == 2) {
          rootv[cc] = gt.hv;
        } else {
          cwr[(size_t)n * 128 + cc] = gt.cv;
          Awr[n][cc] = f2bf(gt.hv);
        }
      }
    }
    __syncthreads();
    R >>= 1;
  }
  if (t < 128) {
    float acc = bout[t];
    const float4* wr = (const float4*)(Wout + t * H_);
    #pragma unroll 4
    for (int k4 = 0; k4 < H_ / 4; ++k4) {
      float4 w4 = wr[k4];
      acc = fmaf(rootv[4 * k4], w4.x, acc); acc = fmaf(rootv[4 * k4 + 1], w4.y, acc);
      acc = fmaf(rootv[4 * k4 + 2], w4.z, acc); acc = fmaf(rootv[4 * k4 + 3], w4.w, acc);
    }
    out[(size_t)b * H_ + t] = acc;
  }
}

extern "C" void kernel_launch(void* const* d_in, const int* in_sizes, int n_in,
                              void* d_out, int out_size, void* d_ws, size_t ws_size,
                              hipStream_t stream) {
  const int* tokens    = (const int*)d_in[0];
  const int* symbols   = (const int*)d_in[1];
  const float* emb     = (const float*)d_in[2];
  const float* sym_emb = (const float*)d_in[3];
  const float* Wp  = (const float*)d_in[4];
  const float* bp  = (const float*)d_in[5];
  const float* Wi  = (const float*)d_in[6];
  const float* bi  = (const float*)d_in[7];
  const float* Ui  = (const float*)d_in[8];
  const float* Wf  = (const float*)d_in[9];
  const float* bf  = (const float*)d_in[10];
  const float* Uf  = (const float*)d_in[11];
  const float* Wo  = (const float*)d_in[12];
  const float* bo  = (const float*)d_in[13];
  const float* Uo  = (const float*)d_in[14];
  const float* Wu  = (const float*)d_in[15];
  const float* bu  = (const float*)d_in[16];
  const float* Uu  = (const float*)d_in[17];
  const float* Wout= (const float*)d_in[18];
  const float* bout= (const float*)d_in[19];

  // Workspace layout
  char* ws = (char*)d_ws;
  unsigned short* Wfrag   = (unsigned short*)(ws);                  // 131072
  float*          leaf_c  = (float*)(ws + 759040);                  // 10752
  float*          symx    = (float*)(ws + 769792);                  // 102400
  float*          P_leaf  = (float*)(ws + 872192);                  // 43008
  unsigned short* tab_h8  = (unsigned short*)(ws + 2001152UL);      // 5644800
  float*          tab_c   = (float*)(ws + 7645952UL);               // 11289600
  int*            idx1    = (int*)(ws + 18935552UL);                // 524288
  unsigned short* L3h8    = (unsigned short*)(ws + 19459840UL);     // 8388608
  float*          L3c     = (float*)(ws + 27848448UL);              // 16777216
  unsigned short* L9h8    = (unsigned short*)(ws + 44625664UL);     // 131072
  float*          L9c     = (float*)(ws + 44756736UL);              // 262144

  k_pre<<<16 + V_ + S_ + 256, 512, 0, stream>>>(
      Ui, Uo, Uu, Uf, Wi, Wo, Wu, Wf, Wp, emb, sym_emb,
      bp, bi, bo, bu, bf, tokens, symbols,
      Wfrag, leaf_c, symx, P_leaf, idx1);
  k_tabB<<<NTAB / 2, 256, 0, stream>>>(P_leaf, symx, leaf_c, tab_h8, tab_c);
  k_lvl23<<<512, 512, 0, stream>>>(Wfrag, symx, symbols, idx1, tab_h8, tab_c,
                                   L3h8, L3c);
  k_mid<<<512, 512, 0, stream>>>(Wfrag, symx, symbols, L3h8, L3c, L9h8, L9c);
  k_fin<<<B_, 512, 0, stream>>>(Wfrag, symx, symbols, L9h8, L9c, Wout, bout,
                                (float*)d_out);
}

// Round 10
// 201.059 us; speedup vs baseline: 1.0819x; 1.0819x over previous
//
#include <hip/hip_runtime.h>
#include <hip/hip_bf16.h>

typedef __attribute__((ext_vector_type(8))) short short8;
typedef __attribute__((ext_vector_type(4))) float f32x4;

static constexpr int B_ = 64;
static constexpr int N_ = 4096;
static constexpr int V_ = 21;
static constexpr int S_ = 50;
static constexpr int E_ = 64;
static constexpr int H_ = 128;
static constexpr int NPAIR = V_ * V_;   // 441
static constexpr int NTAB = NPAIR * S_; // 22050

__device__ __forceinline__ float rcp_(float x) { return __builtin_amdgcn_rcpf(x); }
__device__ __forceinline__ float sigm(float x) { return rcp_(1.0f + __expf(-x)); }
__device__ __forceinline__ float tanh_(float x) {
  float a = fabsf(x);
  float e = __expf(-2.0f * a);
  float t = (1.0f - e) * rcp_(1.0f + e);
  return x < 0.0f ? -t : t;
}
__device__ __forceinline__ unsigned short f2bf(float f) {
  __hip_bfloat16 b = __float2bfloat16(f);
  return *reinterpret_cast<unsigned short*>(&b);
}
__device__ __forceinline__ float bf2f(unsigned short u) {
  return __uint_as_float(((unsigned int)u) << 16);
}

struct Gates { float cv, hv; };
__device__ __forceinline__ Gates gate_combine(float4 sx,
    float i_p, float o_p, float u_p, float fl_p, float fr_p, float cl, float cr) {
  float gi = sigm(sx.x + i_p);
  float go = sigm(sx.y + o_p);
  float gu = tanh_(sx.z + u_p);
  float fl = sigm(sx.w + fl_p);
  float fr = sigm(sx.w + fr_p);
  float cv = fmaf(gi, gu, fmaf(fl, cl, fr * cr));
  Gates g; g.cv = cv; g.hv = go * tanh_(cv);
  return g;
}

// Raw barriers (no vmcnt drain): global prefetches stay in flight across them.
__device__ __forceinline__ void bar_lds() {
  asm volatile("s_waitcnt lgkmcnt(0)" ::: "memory");
  __builtin_amdgcn_s_barrier();
  asm volatile("" ::: "memory");
}
__device__ __forceinline__ void bar_only() {
  asm volatile("" ::: "memory");
  __builtin_amdgcn_s_barrier();
  asm volatile("" ::: "memory");
}

// ---- k_pre: Wfrag build + leaf tables + symx + idx1, all in one launch ----
__global__ void __launch_bounds__(512) k_pre(
    const float* __restrict__ Ui, const float* __restrict__ Uo,
    const float* __restrict__ Uu, const float* __restrict__ Uf,
    const float* __restrict__ Wi, const float* __restrict__ Wo,
    const float* __restrict__ Wu, const float* __restrict__ Wf,
    const float* __restrict__ Wp, const float* __restrict__ emb,
    const float* __restrict__ sym_emb,
    const float* __restrict__ bp, const float* __restrict__ bi,
    const float* __restrict__ bo, const float* __restrict__ bu,
    const float* __restrict__ bfv,
    const int* __restrict__ tokens, const int* __restrict__ symbols,
    unsigned short* __restrict__ Wfrag, float* __restrict__ leaf_c,
    float* __restrict__ symx, float* __restrict__ P_leaf,
    int* __restrict__ idx1) {
  __shared__ float x[128];
  __shared__ float zs[512];
  __shared__ float hl[128];
  int blk = blockIdx.x, t = threadIdx.x;
  if (blk < 16) {
    int idx = blk * 512 + t;  // 8192 frag entries
    int L = idx & 63;
    int K = (idx >> 6) & 3;
    int T = idx >> 8;
    int n = 16 * T + (L & 15);
    int k0 = 32 * K + ((L >> 4) << 3);
    int g = n >> 7, o = n & 127;
    const float* U = (g == 0) ? Ui : (g == 1) ? Uo : (g == 2) ? Uu : Uf;
    unsigned short out[8];
    #pragma unroll
    for (int j = 0; j < 8; ++j) out[j] = f2bf(U[o * 128 + k0 + j]);
    *(int4*)(Wfrag + (size_t)idx * 8) = *(int4*)out;
  } else if (blk < 16 + V_) {
    int v = blk - 16;
    if (t < 128) {
      float acc = bp[t];
      if (v != 0) {  // reference zeroes emb row 0
        const float4* wr = (const float4*)(Wp + t * E_);
        const float4* er = (const float4*)(emb + v * E_);
        #pragma unroll 4
        for (int e4 = 0; e4 < E_ / 4; ++e4) {
          float4 w4 = wr[e4], e4v = er[e4];
          acc = fmaf(e4v.x, w4.x, acc); acc = fmaf(e4v.y, w4.y, acc);
          acc = fmaf(e4v.z, w4.z, acc); acc = fmaf(e4v.w, w4.w, acc);
        }
      }
      x[t] = acc;
    }
    __syncthreads();
    if (t < 384) {  // cols 0..383 = i|o|u
      int g = t >> 7, o = t & 127;
      const float* bb = (g == 0) ? bi : (g == 1) ? bo : bu;
      const float* Wg = (g == 0) ? Wi : (g == 1) ? Wo : Wu;
      float z = bb[o];
      const float4* wr = (const float4*)(Wg + o * H_);
      #pragma unroll 4
      for (int k4 = 0; k4 < H_ / 4; ++k4) {
        float4 w4 = wr[k4];
        z = fmaf(x[4 * k4], w4.x, z); z = fmaf(x[4 * k4 + 1], w4.y, z);
        z = fmaf(x[4 * k4 + 2], w4.z, z); z = fmaf(x[4 * k4 + 3], w4.w, z);
      }
      zs[t] = z;
    }
    __syncthreads();
    if (t < 128) {
      float gi = sigm(zs[t]), go = sigm(zs[128 + t]), gu = tanh_(zs[256 + t]);
      float c = gi * gu;
      leaf_c[v * H_ + t] = c;
      unsigned short hb = f2bf(go * tanh_(c));
      hl[t] = bf2f(hb);
    }
    __syncthreads();
    {  // P_leaf row v: bf16-rounded h x fp32 U, all 512 cols (order i|o|u|f)
      int g = t >> 7, o = t & 127;
      const float* Ug = (g == 0) ? Ui : (g == 1) ? Uo : (g == 2) ? Uu : Uf;
      float z = 0.f;
      const float4* wr = (const float4*)(Ug + o * H_);
      #pragma unroll 4
      for (int k4 = 0; k4 < H_ / 4; ++k4) {
        float4 w4 = wr[k4];
        z = fmaf(hl[4 * k4], w4.x, z); z = fmaf(hl[4 * k4 + 1], w4.y, z);
        z = fmaf(hl[4 * k4 + 2], w4.z, z); z = fmaf(hl[4 * k4 + 3], w4.w, z);
      }
      P_leaf[(size_t)v * 512 + t] = z;
    }
  } else if (blk < 16 + V_ + S_) {
    int s = blk - 16 - V_;
    if (t < 128) {
      float acc = bp[t];
      const float4* wr = (const float4*)(Wp + t * E_);
      const float4* er = (const float4*)(sym_emb + s * E_);
      #pragma unroll 4
      for (int e4 = 0; e4 < E_ / 4; ++e4) {
        float4 w4 = wr[e4], e4v = er[e4];
        acc = fmaf(e4v.x, w4.x, acc); acc = fmaf(e4v.y, w4.y, acc);
        acc = fmaf(e4v.z, w4.z, acc); acc = fmaf(e4v.w, w4.w, acc);
      }
      x[t] = acc;
    }
    __syncthreads();
    {
      int g = t >> 7, o = t & 127;
      const float* bb = (g == 0) ? bi : (g == 1) ? bo : (g == 2) ? bu : bfv;
      const float* Wg = (g == 0) ? Wi : (g == 1) ? Wo : (g == 2) ? Wu : Wf;
      float z = bb[o];
      const float4* wr = (const float4*)(Wg + o * H_);
      #pragma unroll 4
      for (int k4 = 0; k4 < H_ / 4; ++k4) {
        float4 w4 = wr[k4];
        z = fmaf(x[4 * k4], w4.x, z); z = fmaf(x[4 * k4 + 1], w4.y, z);
        z = fmaf(x[4 * k4 + 2], w4.z, z); z = fmaf(x[4 * k4 + 3], w4.w, z);
      }
      zs[t] = z;
    }
    __syncthreads();
    if (t < 128) {
      float4 v4 = make_float4(zs[t], zs[128 + t], zs[256 + t], zs[384 + t]);
      *(float4*)(symx + (size_t)s * 512 + t * 4) = v4;
    }
  } else {
    int g = (blk - 16 - V_ - S_) * 512 + t;   // 131072 level-1 nodes
    int b = g >> 11, j = g & 2047;
    idx1[g] = (tokens[b * N_ + 2 * j] * V_ + tokens[b * N_ + 2 * j + 1]) * S_
              + symbols[b * (N_ - 1) + j];
  }
}

// ---- tabB: gate epilogue over 22050 rows (gathering from P_leaf) ----
__global__ void k_tabB(const float* __restrict__ P_leaf, const float* __restrict__ symx,
                       const float* __restrict__ leaf_c,
                       unsigned short* __restrict__ tab_h8, float* __restrict__ tab_c) {
  int blk = blockIdx.x, t = threadIdx.x;
  int row = blk * 2 + (t >> 7);
  int u = t & 127;
  int p = row / S_, s = row - p * S_;
  int tl = p / V_, tr = p - tl * V_;
  const float* Pl = P_leaf + (size_t)tl * 512;
  const float* Pr = P_leaf + (size_t)tr * 512;
  float4 sx = *(const float4*)(symx + (size_t)s * 512 + u * 4);
  Gates gt = gate_combine(sx,
      Pl[u] + Pr[u], Pl[128 + u] + Pr[128 + u], Pl[256 + u] + Pr[256 + u],
      Pl[384 + u], Pr[384 + u],
      leaf_c[tl * H_ + u], leaf_c[tr * H_ + u]);
  tab_c[(size_t)row * H_ + u] = gt.cv;
  tab_h8[(size_t)row * H_ + u] = f2bf(gt.hv);
}

// ---- fused levels 2+3: PERSISTENT blocks (grid 512 x CH 8), DEEP pipeline:
// h-row, child-c VALUES, and indices all prefetched one tile ahead (~2500cy
// cover vs L3 ~600-900cy). Hoisted weights, raw barriers, dual-half phase 1.
// NO launch_bounds min (r1/r7 spills); kernel runs 1 block/CU -> regs are free.
__global__ void __launch_bounds__(512) k_lvl23(
    const unsigned short* __restrict__ Wfrag, const float* __restrict__ symx,
    const int* __restrict__ symbols, const int* __restrict__ idx1,
    const unsigned short* __restrict__ gh8, const float* __restrict__ gc,
    unsigned short* __restrict__ h_out8, float* __restrict__ c_out) {
  __shared__ __align__(16) unsigned short Ag[32][136];
  __shared__ __align__(16) unsigned short Bh[16][136];
  __shared__ float Bc[16][132];
  const int t = threadIdx.x;
  const int w = t >> 6, L = t & 63, q = L >> 4, cL = L & 15;
  const int cc = 16 * w + cL;
  const int rowA = t >> 4, coA = (t & 15) * 8;

  // hoist weight fragments once per block
  const short8* wf = (const short8*)Wfrag;
  short8 bfr[4][4];
  #pragma unroll
  for (int K = 0; K < 4; ++K)
    #pragma unroll
    for (int g = 0; g < 4; ++g)
      bfr[g][K] = wf[(size_t)((w + 8 * g) * 4 + K) * 64 + L];

  const int CH = 8;                   // tiles per block; grid = 512
  const int t0 = blockIdx.x * CH;

  int nn[4];
  #pragma unroll
  for (int it = 0; it < 4; ++it) nn[it] = 8 * (it >> 1) + 2 * q + (it & 1);

  // ---- prologue: fully prefetch tile t0 (h-row + c-values + symbols) ----
  int4 agv;
  float clp[4], crp[4];
  int sp1[4];
  {
    int gxr = idx1[t0 * 32 + rowA];
    agv = *(const int4*)(gh8 + (size_t)gxr * H_ + coA);
    const int* sb = symbols + (size_t)(t0 >> 6) * (N_ - 1);
    const int j20 = (t0 & 63) * 16;
    #pragma unroll
    for (int it = 0; it < 4; ++it) {
      int g2l = idx1[t0 * 32 + 2 * nn[it]];
      int g2r = idx1[t0 * 32 + 2 * nn[it] + 1];
      clp[it] = gc[(size_t)g2l * H_ + cc];
      crp[it] = gc[(size_t)g2r * H_ + cc];
      sp1[it] = sb[2048 + j20 + nn[it]];
    }
  }

  for (int k = 0; k < CH; ++k) {
    const int tile = t0 + k;
    const int j2 = (tile & 63) * 16;
    const int* sb = symbols + (size_t)(tile >> 6) * (N_ - 1);
    const bool hasNext = (k + 1 < CH);

    bar_only();                       // prev phase-2 done with Bh/Bc; Ag free
    *(int4*)&Ag[rowA][coA] = agv;
    bar_lds();                        // Ag visible to all waves

    // next-tile index loads (L2-hot); value gathers issued mid-phase-1
    int gxr_n = 0, g2l_n[4], g2r_n[4], sp1_n[4];
    if (hasNext) {
      const int tn = tile + 1;
      const int* sbn = symbols + (size_t)(tn >> 6) * (N_ - 1);
      const int j2n = (tn & 63) * 16;
      gxr_n = idx1[tn * 32 + rowA];
      #pragma unroll
      for (int it = 0; it < 4; ++it) {
        g2l_n[it] = idx1[tn * 32 + 2 * nn[it]];
        g2r_n[it] = idx1[tn * 32 + 2 * nn[it] + 1];
        sp1_n[it] = sbn[2048 + j2n + nn[it]];
      }
    }
    int sp2[2];
    sp2[0] = sb[3072 + (j2 >> 1) + 2 * q];
    sp2[1] = sb[3072 + (j2 >> 1) + 2 * q + 1];

    // ---- phase 1: 16 L2 nodes ----
    f32x4 acc[2][4];
    #pragma unroll
    for (int r = 0; r < 2; ++r)
      #pragma unroll
      for (int g = 0; g < 4; ++g) acc[r][g] = (f32x4){0.f, 0.f, 0.f, 0.f};
    #pragma unroll
    for (int K = 0; K < 4; ++K) {
      short8 a0 = *(const short8*)&Ag[cL][K * 32 + q * 8];
      short8 a1 = *(const short8*)&Ag[16 + cL][K * 32 + q * 8];
      #pragma unroll
      for (int g = 0; g < 4; ++g) {
        acc[0][g] = __builtin_amdgcn_mfma_f32_16x16x32_bf16(a0, bfr[g][K], acc[0][g], 0, 0, 0);
        acc[1][g] = __builtin_amdgcn_mfma_f32_16x16x32_bf16(a1, bfr[g][K], acc[1][g], 0, 0, 0);
      }
    }
    // issue next tile's long-latency gathers (h-row + c-values); they land
    // during phase 2 / next iteration (~2500 cy of cover).
    float clp_n[4], crp_n[4];
    if (hasNext) {
      agv = *(const int4*)(gh8 + (size_t)gxr_n * H_ + coA);
      #pragma unroll
      for (int it = 0; it < 4; ++it) {
        clp_n[it] = gc[(size_t)g2l_n[it] * H_ + cc];
        crp_n[it] = gc[(size_t)g2r_n[it] * H_ + cc];
      }
    }

    #pragma unroll
    for (int r = 0; r < 2; ++r) {
      #pragma unroll
      for (int nd = 0; nd < 2; ++nd) {
        int it = r * 2 + nd;
        int n = 8 * r + 2 * q + nd;
        float4 sx = *(const float4*)(symx + (size_t)sp1[it] * 512 + cc * 4);
        Gates gt = gate_combine(sx,
            acc[r][0][2 * nd] + acc[r][0][2 * nd + 1],
            acc[r][1][2 * nd] + acc[r][1][2 * nd + 1],
            acc[r][2][2 * nd] + acc[r][2][2 * nd + 1],
            acc[r][3][2 * nd], acc[r][3][2 * nd + 1], clp[it], crp[it]);
        Bc[n][cc] = gt.cv;
        Bh[n][cc] = f2bf(gt.hv);
      }
    }
    bar_lds();                        // Bh/Bc visible

    // ---- phase 2: 8 L3 nodes ----
    f32x4 acc2[4];
    #pragma unroll
    for (int g = 0; g < 4; ++g) acc2[g] = (f32x4){0.f, 0.f, 0.f, 0.f};
    #pragma unroll
    for (int K = 0; K < 4; ++K) {
      short8 a0 = *(const short8*)&Bh[cL][K * 32 + q * 8];
      #pragma unroll
      for (int g = 0; g < 4; ++g)
        acc2[g] = __builtin_amdgcn_mfma_f32_16x16x32_bf16(a0, bfr[g][K], acc2[g], 0, 0, 0);
    }
    #pragma unroll
    for (int nd = 0; nd < 2; ++nd) {
      int n = 2 * q + nd;
      int G3 = tile * 8 + n;
      float4 sx = *(const float4*)(symx + (size_t)sp2[nd] * 512 + cc * 4);
      Gates gt = gate_combine(sx,
          acc2[0][2 * nd] + acc2[0][2 * nd + 1],
          acc2[1][2 * nd] + acc2[1][2 * nd + 1],
          acc2[2][2 * nd] + acc2[2][2 * nd + 1],
          acc2[3][2 * nd], acc2[3][2 * nd + 1],
          Bc[2 * n][cc], Bc[2 * n + 1][cc]);
      c_out[(size_t)G3 * H_ + cc] = gt.cv;
      h_out8[(size_t)G3 * H_ + cc] = f2bf(gt.hv);
    }
    // rotate prefetched values
    #pragma unroll
    for (int it = 0; it < 4; ++it) {
      clp[it] = clp_n[it]; crp[it] = crp_n[it]; sp1[it] = sp1_n[it];
    }
  }
}

// ---- k_mid: levels 4-9 fused; 512 blocks, subtree-local, LDS ping-pong ----
__global__ void __launch_bounds__(512, 2) k_mid(
    const unsigned short* __restrict__ Wfrag, const float* __restrict__ symx,
    const int* __restrict__ symbols,
    const unsigned short* __restrict__ in_h8, const float* __restrict__ in_c,
    unsigned short* __restrict__ out_h8, float* __restrict__ out_c) {
  __shared__ __align__(16) unsigned short Ah0[64][136];
  __shared__ __align__(16) unsigned short Ah1[32][136];
  __shared__ float Cs0[64][128];
  __shared__ float Cs1[32][128];
  int t = threadIdx.x;
  int w = t >> 6, L = t & 63, q = L >> 4, cL = L & 15;
  int cc = 16 * w + cL;
  int blk = blockIdx.x;
  int b = blk >> 3, sub = blk & 7;
  size_t base3 = (size_t)blk * 64;

  #pragma unroll
  for (int i = 0; i < 2; ++i) {
    int fid = t + 512 * i;
    int row = fid >> 4, co = (fid & 15) * 8;
    *(int4*)&Ah0[row][co] = *(const int4*)(in_h8 + (base3 + row) * H_ + co);
  }
  #pragma unroll
  for (int i = 0; i < 4; ++i) {
    int fid = t + 512 * i;
    int row = fid >> 5, c4 = (fid & 31) << 2;
    *(float4*)&Cs0[row][c4] = *(const float4*)(in_c + (base3 + row) * H_ + c4);
  }
  __syncthreads();

  const short8* wf = (const short8*)Wfrag;
  int R = 64;
  #pragma unroll
  for (int lev = 0; lev < 6; ++lev) {
    const int l = 4 + lev;
    const int nodes = R >> 1;
    const int jb = b * (N_ - 1) + (N_ - (N_ >> (l - 1))) + ((sub * 32) >> lev);
    unsigned short (*Ard)[136] = (lev & 1) ? Ah1 : Ah0;
    unsigned short (*Awr)[136] = (lev & 1) ? Ah0 : Ah1;
    const float* crd = (lev & 1) ? &Cs1[0][0] : &Cs0[0][0];
    float* cwr = (lev & 1) ? &Cs0[0][0] : &Cs1[0][0];
    const int nchunk = (nodes + 15) >> 4;
    for (int c = 0; c < nchunk; ++c) {
      int spre[4];
      #pragma unroll
      for (int it = 0; it < 4; ++it) {
        int n = 16 * c + 8 * (it >> 1) + 2 * q + (it & 1);
        spre[it] = (n < nodes) ? symbols[jb + n] : 0;
      }
      f32x4 acc[2][4];
      #pragma unroll
      for (int r = 0; r < 2; ++r)
        #pragma unroll
        for (int g = 0; g < 4; ++g) acc[r][g] = (f32x4){0.f, 0.f, 0.f, 0.f};
      const bool useA1 = (2 * nodes - 32 * c) > 16;
      #pragma unroll
      for (int K = 0; K < 4; ++K) {
        short8 bfr[4];
        #pragma unroll
        for (int g = 0; g < 4; ++g) bfr[g] = wf[(size_t)((w + 8 * g) * 4 + K) * 64 + L];
        short8 a0 = *(const short8*)&Ard[32 * c + cL][K * 32 + q * 8];
        #pragma unroll
        for (int g = 0; g < 4; ++g)
          acc[0][g] = __builtin_amdgcn_mfma_f32_16x16x32_bf16(a0, bfr[g], acc[0][g], 0, 0, 0);
        if (useA1) {
          short8 a1 = *(const short8*)&Ard[32 * c + 16 + cL][K * 32 + q * 8];
          #pragma unroll
          for (int g = 0; g < 4; ++g)
            acc[1][g] = __builtin_amdgcn_mfma_f32_16x16x32_bf16(a1, bfr[g], acc[1][g], 0, 0, 0);
        }
      }
      #pragma unroll
      for (int r = 0; r < 2; ++r) {
        #pragma unroll
        for (int nd = 0; nd < 2; ++nd) {
          int it = r * 2 + nd;
          int n = 16 * c + 8 * r + 2 * q + nd;
          if (n < nodes) {
            float4 sx = *(const float4*)(symx + (size_t)spre[it] * 512 + cc * 4);
            Gates gt = gate_combine(sx,
                acc[r][0][2 * nd] + acc[r][0][2 * nd + 1],
                acc[r][1][2 * nd] + acc[r][1][2 * nd + 1],
                acc[r][2][2 * nd] + acc[r][2][2 * nd + 1],
                acc[r][3][2 * nd], acc[r][3][2 * nd + 1],
                crd[(size_t)(2 * n) * 128 + cc], crd[(size_t)(2 * n + 1) * 128 + cc]);
            if (lev == 5) {
              out_c[(size_t)blk * H_ + cc] = gt.cv;
              out_h8[(size_t)blk * H_ + cc] = f2bf(gt.hv);
            } else {
              cwr[(size_t)n * 128 + cc] = gt.cv;
              Awr[n][cc] = f2bf(gt.hv);
            }
          }
        }
      }
    }
    __syncthreads();
    R >>= 1;
  }
}

// ---- k_fin: levels 10-12 + fused projection (direct Wout rows); 64 blocks ----
__global__ void __launch_bounds__(512, 2) k_fin(
    const unsigned short* __restrict__ Wfrag, const float* __restrict__ symx,
    const int* __restrict__ symbols,
    const unsigned short* __restrict__ in_h8, const float* __restrict__ in_c,
    const float* __restrict__ Wout, const float* __restrict__ bout,
    float* __restrict__ out) {
  __shared__ __align__(16) unsigned short Ah0[8][136];
  __shared__ __align__(16) unsigned short Ah1[4][136];
  __shared__ float Cs0[8][128];
  __shared__ float Cs1[4][128];
  __shared__ float rootv[128];
  int t = threadIdx.x;
  int w = t >> 6, L = t & 63, q = L >> 4, cL = L & 15;
  int cc = 16 * w + cL;
  int b = blockIdx.x;

  if (t < 128) {
    int row = t >> 4, co = (t & 15) * 8;
    *(int4*)&Ah0[row][co] = *(const int4*)(in_h8 + (size_t)(b * 8 + row) * H_ + co);
  }
  if (t < 256) {
    int row = t >> 5, c4 = (t & 31) << 2;
    *(float4*)&Cs0[row][c4] = *(const float4*)(in_c + (size_t)(b * 8 + row) * H_ + c4);
  }
  __syncthreads();

  const short8* wf = (const short8*)Wfrag;
  int R = 8;
  #pragma unroll
  for (int lev = 0; lev < 3; ++lev) {
    const int l = 10 + lev;
    const int nodes = R >> 1;
    const int jb = b * (N_ - 1) + (N_ - (N_ >> (l - 1)));
    unsigned short (*Ard)[136] = (lev & 1) ? Ah1 : Ah0;
    unsigned short (*Awr)[136] = (lev & 1) ? Ah0 : Ah1;
    const float* crd = (lev & 1) ? &Cs1[0][0] : &Cs0[0][0];
    float* cwr = (lev & 1) ? &Cs0[0][0] : &Cs1[0][0];
    int spre[4];
    #pragma unroll
    for (int it = 0; it < 4; ++it) {
      int n = 8 * (it >> 1) + 2 * q + (it & 1);
      spre[it] = (n < nodes) ? symbols[jb + n] : 0;
    }
    f32x4 acc[4];
    #pragma unroll
    for (int g = 0; g < 4; ++g) acc[g] = (f32x4){0.f, 0.f, 0.f, 0.f};
    #pragma unroll
    for (int K = 0; K < 4; ++K) {
      short8 bfr[4];
      #pragma unroll
      for (int g = 0; g < 4; ++g) bfr[g] = wf[(size_t)((w + 8 * g) * 4 + K) * 64 + L];
      short8 a0 = *(const short8*)&Ard[cL & 7][K * 32 + q * 8];
      #pragma unroll
      for (int g = 0; g < 4; ++g)
        acc[g] = __builtin_amdgcn_mfma_f32_16x16x32_bf16(a0, bfr[g], acc[g], 0, 0, 0);
    }
    #pragma unroll
    for (int nd = 0; nd < 2; ++nd) {
      int it = nd;
      int n = 2 * q + nd;
      if (n < nodes) {
        float4 sx = *(const float4*)(symx + (size_t)spre[it] * 512 + cc * 4);
        Gates gt = gate_combine(sx,
            acc[0][2 * nd] + acc[0][2 * nd + 1],
            acc[1][2 * nd] + acc[1][2 * nd + 1],
            acc[2][2 * nd] + acc[2][2 * nd + 1],
            acc[3][2 * nd], acc[3][2 * nd + 1],
            crd[(size_t)(2 * n) * 128 + cc], crd[(size_t)(2 * n + 1) * 128 + cc]);
        if (lev == 2) {
          rootv[cc] = gt.hv;
        } else {
          cwr[(size_t)n * 128 + cc] = gt.cv;
          Awr[n][cc] = f2bf(gt.hv);
        }
      }
    }
    __syncthreads();
    R >>= 1;
  }
  if (t < 128) {
    float acc = bout[t];
    const float4* wr = (const float4*)(Wout + t * H_);
    #pragma unroll 4
    for (int k4 = 0; k4 < H_ / 4; ++k4) {
      float4 w4 = wr[k4];
      acc = fmaf(rootv[4 * k4], w4.x, acc); acc = fmaf(rootv[4 * k4 + 1], w4.y, acc);
      acc = fmaf(rootv[4 * k4 + 2], w4.z, acc); acc = fmaf(rootv[4 * k4 + 3], w4.w, acc);
    }
    out[(size_t)b * H_ + t] = acc;
  }
}

extern "C" void kernel_launch(void* const* d_in, const int* in_sizes, int n_in,
                              void* d_out, int out_size, void* d_ws, size_t ws_size,
                              hipStream_t stream) {
  const int* tokens    = (const int*)d_in[0];
  const int* symbols   = (const int*)d_in[1];
  const float* emb     = (const float*)d_in[2];
  const float* sym_emb = (const float*)d_in[3];
  const float* Wp  = (const float*)d_in[4];
  const float* bp  = (const float*)d_in[5];
  const float* Wi  = (const float*)d_in[6];
  const float* bi  = (const float*)d_in[7];
  const float* Ui  = (const float*)d_in[8];
  const float* Wf  = (const float*)d_in[9];
  const float* bf  = (const float*)d_in[10];
  const float* Uf  = (const float*)d_in[11];
  const float* Wo  = (const float*)d_in[12];
  const float* bo  = (const float*)d_in[13];
  const float* Uo  = (const float*)d_in[14];
  const float* Wu  = (const float*)d_in[15];
  const float* bu  = (const float*)d_in[16];
  const float* Uu  = (const float*)d_in[17];
  const float* Wout= (const float*)d_in[18];
  const float* bout= (const float*)d_in[19];

  // Workspace layout
  char* ws = (char*)d_ws;
  unsigned short* Wfrag   = (unsigned short*)(ws);                  // 131072
  float*          leaf_c  = (float*)(ws + 759040);                  // 10752
  float*          symx    = (float*)(ws + 769792);                  // 102400
  float*          P_leaf  = (float*)(ws + 872192);                  // 43008
  unsigned short* tab_h8  = (unsigned short*)(ws + 2001152UL);      // 5644800
  float*          tab_c   = (float*)(ws + 7645952UL);               // 11289600
  int*            idx1    = (int*)(ws + 18935552UL);                // 524288
  unsigned short* L3h8    = (unsigned short*)(ws + 19459840UL);     // 8388608
  float*          L3c     = (float*)(ws + 27848448UL);              // 16777216
  unsigned short* L9h8    = (unsigned short*)(ws + 44625664UL);     // 131072
  float*          L9c     = (float*)(ws + 44756736UL);              // 262144

  k_pre<<<16 + V_ + S_ + 256, 512, 0, stream>>>(
      Ui, Uo, Uu, Uf, Wi, Wo, Wu, Wf, Wp, emb, sym_emb,
      bp, bi, bo, bu, bf, tokens, symbols,
      Wfrag, leaf_c, symx, P_leaf, idx1);
  k_tabB<<<NTAB / 2, 256, 0, stream>>>(P_leaf, symx, leaf_c, tab_h8, tab_c);
  k_lvl23<<<512, 512, 0, stream>>>(Wfrag, symx, symbols, idx1, tab_h8, tab_c,
                                   L3h8, L3c);
  k_mid<<<512, 512, 0, stream>>>(Wfrag, symx, symbols, L3h8, L3c, L9h8, L9c);
  k_fin<<<B_, 512, 0, stream>>>(Wfrag, symx, symbols, L9h8, L9c, Wout, bout,
                                (float*)d_out);
}

// Round 11
// 197.237 us; speedup vs baseline: 1.1029x; 1.0194x over previous
//
#include <hip/hip_runtime.h>
#include <hip/hip_bf16.h>

typedef __attribute__((ext_vector_type(8))) short short8;
typedef __attribute__((ext_vector_type(4))) float f32x4;

static constexpr int B_ = 64;
static constexpr int N_ = 4096;
static constexpr int V_ = 21;
static constexpr int S_ = 50;
static constexpr int E_ = 64;
static constexpr int H_ = 128;
static constexpr int NPAIR = V_ * V_;   // 441
static constexpr int NTAB = NPAIR * S_; // 22050

__device__ __forceinline__ float rcp_(float x) { return __builtin_amdgcn_rcpf(x); }
__device__ __forceinline__ float sigm(float x) { return rcp_(1.0f + __expf(-x)); }
__device__ __forceinline__ float tanh_(float x) {
  float a = fabsf(x);
  float e = __expf(-2.0f * a);
  float t = (1.0f - e) * rcp_(1.0f + e);
  return x < 0.0f ? -t : t;
}
__device__ __forceinline__ unsigned short f2bf(float f) {
  __hip_bfloat16 b = __float2bfloat16(f);
  return *reinterpret_cast<unsigned short*>(&b);
}
__device__ __forceinline__ float bf2f(unsigned short u) {
  return __uint_as_float(((unsigned int)u) << 16);
}

struct Gates { float cv, hv; };
__device__ __forceinline__ Gates gate_combine(float4 sx,
    float i_p, float o_p, float u_p, float fl_p, float fr_p, float cl, float cr) {
  float gi = sigm(sx.x + i_p);
  float go = sigm(sx.y + o_p);
  float gu = tanh_(sx.z + u_p);
  float fl = sigm(sx.w + fl_p);
  float fr = sigm(sx.w + fr_p);
  float cv = fmaf(gi, gu, fmaf(fl, cl, fr * cr));
  Gates g; g.cv = cv; g.hv = go * tanh_(cv);
  return g;
}

// Raw barriers (no vmcnt drain): global prefetches stay in flight across them.
__device__ __forceinline__ void bar_lds() {
  asm volatile("s_waitcnt lgkmcnt(0)" ::: "memory");
  __builtin_amdgcn_s_barrier();
  asm volatile("" ::: "memory");
}
__device__ __forceinline__ void bar_only() {
  asm volatile("" ::: "memory");
  __builtin_amdgcn_s_barrier();
  asm volatile("" ::: "memory");
}

// ---- k_pre: Wfrag build + leaf tables + symx + idx1, all in one launch ----
__global__ void __launch_bounds__(512) k_pre(
    const float* __restrict__ Ui, const float* __restrict__ Uo,
    const float* __restrict__ Uu, const float* __restrict__ Uf,
    const float* __restrict__ Wi, const float* __restrict__ Wo,
    const float* __restrict__ Wu, const float* __restrict__ Wf,
    const float* __restrict__ Wp, const float* __restrict__ emb,
    const float* __restrict__ sym_emb,
    const float* __restrict__ bp, const float* __restrict__ bi,
    const float* __restrict__ bo, const float* __restrict__ bu,
    const float* __restrict__ bfv,
    const int* __restrict__ tokens, const int* __restrict__ symbols,
    unsigned short* __restrict__ Wfrag, float* __restrict__ leaf_c,
    float* __restrict__ symx, float* __restrict__ P_leaf,
    int* __restrict__ idx1) {
  __shared__ float x[128];
  __shared__ float zs[512];
  __shared__ float hl[128];
  int blk = blockIdx.x, t = threadIdx.x;
  if (blk < 16) {
    int idx = blk * 512 + t;  // 8192 frag entries
    int L = idx & 63;
    int K = (idx >> 6) & 3;
    int T = idx >> 8;
    int n = 16 * T + (L & 15);
    int k0 = 32 * K + ((L >> 4) << 3);
    int g = n >> 7, o = n & 127;
    const float* U = (g == 0) ? Ui : (g == 1) ? Uo : (g == 2) ? Uu : Uf;
    unsigned short out[8];
    #pragma unroll
    for (int j = 0; j < 8; ++j) out[j] = f2bf(U[o * 128 + k0 + j]);
    *(int4*)(Wfrag + (size_t)idx * 8) = *(int4*)out;
  } else if (blk < 16 + V_) {
    int v = blk - 16;
    if (t < 128) {
      float acc = bp[t];
      if (v != 0) {  // reference zeroes emb row 0
        const float4* wr = (const float4*)(Wp + t * E_);
        const float4* er = (const float4*)(emb + v * E_);
        #pragma unroll 4
        for (int e4 = 0; e4 < E_ / 4; ++e4) {
          float4 w4 = wr[e4], e4v = er[e4];
          acc = fmaf(e4v.x, w4.x, acc); acc = fmaf(e4v.y, w4.y, acc);
          acc = fmaf(e4v.z, w4.z, acc); acc = fmaf(e4v.w, w4.w, acc);
        }
      }
      x[t] = acc;
    }
    __syncthreads();
    if (t < 384) {  // cols 0..383 = i|o|u
      int g = t >> 7, o = t & 127;
      const float* bb = (g == 0) ? bi : (g == 1) ? bo : bu;
      const float* Wg = (g == 0) ? Wi : (g == 1) ? Wo : Wu;
      float z = bb[o];
      const float4* wr = (const float4*)(Wg + o * H_);
      #pragma unroll 4
      for (int k4 = 0; k4 < H_ / 4; ++k4) {
        float4 w4 = wr[k4];
        z = fmaf(x[4 * k4], w4.x, z); z = fmaf(x[4 * k4 + 1], w4.y, z);
        z = fmaf(x[4 * k4 + 2], w4.z, z); z = fmaf(x[4 * k4 + 3], w4.w, z);
      }
      zs[t] = z;
    }
    __syncthreads();
    if (t < 128) {
      float gi = sigm(zs[t]), go = sigm(zs[128 + t]), gu = tanh_(zs[256 + t]);
      float c = gi * gu;
      leaf_c[v * H_ + t] = c;
      unsigned short hb = f2bf(go * tanh_(c));
      hl[t] = bf2f(hb);
    }
    __syncthreads();
    {  // P_leaf row v: bf16-rounded h x fp32 U, all 512 cols (order i|o|u|f)
      int g = t >> 7, o = t & 127;
      const float* Ug = (g == 0) ? Ui : (g == 1) ? Uo : (g == 2) ? Uu : Uf;
      float z = 0.f;
      const float4* wr = (const float4*)(Ug + o * H_);
      #pragma unroll 4
      for (int k4 = 0; k4 < H_ / 4; ++k4) {
        float4 w4 = wr[k4];
        z = fmaf(hl[4 * k4], w4.x, z); z = fmaf(hl[4 * k4 + 1], w4.y, z);
        z = fmaf(hl[4 * k4 + 2], w4.z, z); z = fmaf(hl[4 * k4 + 3], w4.w, z);
      }
      P_leaf[(size_t)v * 512 + t] = z;
    }
  } else if (blk < 16 + V_ + S_) {
    int s = blk - 16 - V_;
    if (t < 128) {
      float acc = bp[t];
      const float4* wr = (const float4*)(Wp + t * E_);
      const float4* er = (const float4*)(sym_emb + s * E_);
      #pragma unroll 4
      for (int e4 = 0; e4 < E_ / 4; ++e4) {
        float4 w4 = wr[e4], e4v = er[e4];
        acc = fmaf(e4v.x, w4.x, acc); acc = fmaf(e4v.y, w4.y, acc);
        acc = fmaf(e4v.z, w4.z, acc); acc = fmaf(e4v.w, w4.w, acc);
      }
      x[t] = acc;
    }
    __syncthreads();
    {
      int g = t >> 7, o = t & 127;
      const float* bb = (g == 0) ? bi : (g == 1) ? bo : (g == 2) ? bu : bfv;
      const float* Wg = (g == 0) ? Wi : (g == 1) ? Wo : (g == 2) ? Wu : Wf;
      float z = bb[o];
      const float4* wr = (const float4*)(Wg + o * H_);
      #pragma unroll 4
      for (int k4 = 0; k4 < H_ / 4; ++k4) {
        float4 w4 = wr[k4];
        z = fmaf(x[4 * k4], w4.x, z); z = fmaf(x[4 * k4 + 1], w4.y, z);
        z = fmaf(x[4 * k4 + 2], w4.z, z); z = fmaf(x[4 * k4 + 3], w4.w, z);
      }
      zs[t] = z;
    }
    __syncthreads();
    if (t < 128) {
      float4 v4 = make_float4(zs[t], zs[128 + t], zs[256 + t], zs[384 + t]);
      *(float4*)(symx + (size_t)s * 512 + t * 4) = v4;
    }
  } else {
    int g = (blk - 16 - V_ - S_) * 512 + t;   // 131072 level-1 nodes
    int b = g >> 11, j = g & 2047;
    idx1[g] = (tokens[b * N_ + 2 * j] * V_ + tokens[b * N_ + 2 * j + 1]) * S_
              + symbols[b * (N_ - 1) + j];
  }
}

// ---- tabB: gate epilogue over 22050 rows (gathering from P_leaf) ----
__global__ void k_tabB(const float* __restrict__ P_leaf, const float* __restrict__ symx,
                       const float* __restrict__ leaf_c,
                       unsigned short* __restrict__ tab_h8, float* __restrict__ tab_c) {
  int blk = blockIdx.x, t = threadIdx.x;
  int row = blk * 2 + (t >> 7);
  int u = t & 127;
  int p = row / S_, s = row - p * S_;
  int tl = p / V_, tr = p - tl * V_;
  const float* Pl = P_leaf + (size_t)tl * 512;
  const float* Pr = P_leaf + (size_t)tr * 512;
  float4 sx = *(const float4*)(symx + (size_t)s * 512 + u * 4);
  Gates gt = gate_combine(sx,
      Pl[u] + Pr[u], Pl[128 + u] + Pr[128 + u], Pl[256 + u] + Pr[256 + u],
      Pl[384 + u], Pr[384 + u],
      leaf_c[tl * H_ + u], leaf_c[tr * H_ + u]);
  tab_c[(size_t)row * H_ + u] = gt.cv;
  tab_h8[(size_t)row * H_ + u] = f2bf(gt.hv);
}

// ---- fused levels 2+3: PERSISTENT blocks (grid 512 x CH 8), FULL pipeline:
// h-row, child-c values, AND symx gate-vectors all prefetched one tile ahead.
// Epilogues are pure-register VALU. Hoisted weights, raw barriers.
// NO launch_bounds min (r1/r7 spills); 1 block/CU -> regs are free (<256).
__global__ void __launch_bounds__(512) k_lvl23(
    const unsigned short* __restrict__ Wfrag, const float* __restrict__ symx,
    const int* __restrict__ symbols, const int* __restrict__ idx1,
    const unsigned short* __restrict__ gh8, const float* __restrict__ gc,
    unsigned short* __restrict__ h_out8, float* __restrict__ c_out) {
  __shared__ __align__(16) unsigned short Ag[32][136];
  __shared__ __align__(16) unsigned short Bh[16][136];
  __shared__ float Bc[16][132];
  const int t = threadIdx.x;
  const int w = t >> 6, L = t & 63, q = L >> 4, cL = L & 15;
  const int cc = 16 * w + cL;
  const int rowA = t >> 4, coA = (t & 15) * 8;

  // hoist weight fragments once per block
  const short8* wf = (const short8*)Wfrag;
  short8 bfr[4][4];
  #pragma unroll
  for (int K = 0; K < 4; ++K)
    #pragma unroll
    for (int g = 0; g < 4; ++g)
      bfr[g][K] = wf[(size_t)((w + 8 * g) * 4 + K) * 64 + L];

  const int CH = 8;                   // tiles per block; grid = 512
  const int t0 = blockIdx.x * CH;

  int nn[4];
  #pragma unroll
  for (int it = 0; it < 4; ++it) nn[it] = 8 * (it >> 1) + 2 * q + (it & 1);

  // ---- prologue: fully prefetch tile t0 (h-row, c-values, symx values) ----
  int4 agv;
  float clp[4], crp[4];
  float4 sx1[4], sx2[2];
  {
    int gxr = idx1[t0 * 32 + rowA];
    agv = *(const int4*)(gh8 + (size_t)gxr * H_ + coA);
    const int* sb = symbols + (size_t)(t0 >> 6) * (N_ - 1);
    const int j20 = (t0 & 63) * 16;
    #pragma unroll
    for (int it = 0; it < 4; ++it) {
      int g2l = idx1[t0 * 32 + 2 * nn[it]];
      int g2r = idx1[t0 * 32 + 2 * nn[it] + 1];
      clp[it] = gc[(size_t)g2l * H_ + cc];
      crp[it] = gc[(size_t)g2r * H_ + cc];
      int sp = sb[2048 + j20 + nn[it]];
      sx1[it] = *(const float4*)(symx + (size_t)sp * 512 + cc * 4);
    }
    #pragma unroll
    for (int nd = 0; nd < 2; ++nd) {
      int sp = sb[3072 + (j20 >> 1) + 2 * q + nd];
      sx2[nd] = *(const float4*)(symx + (size_t)sp * 512 + cc * 4);
    }
  }

  for (int k = 0; k < CH; ++k) {
    const int tile = t0 + k;
    const bool hasNext = (k + 1 < CH);

    bar_only();                       // prev phase-2 done with Bh/Bc; Ag free
    *(int4*)&Ag[rowA][coA] = agv;
    bar_lds();                        // Ag visible to all waves

    // next-tile index loads (L2-hot); value gathers issued mid-phase-1
    int gxr_n = 0, g2l_n[4], g2r_n[4], sp1_n[4], sp2_n[2];
    if (hasNext) {
      const int tn = tile + 1;
      const int* sbn = symbols + (size_t)(tn >> 6) * (N_ - 1);
      const int j2n = (tn & 63) * 16;
      gxr_n = idx1[tn * 32 + rowA];
      #pragma unroll
      for (int it = 0; it < 4; ++it) {
        g2l_n[it] = idx1[tn * 32 + 2 * nn[it]];
        g2r_n[it] = idx1[tn * 32 + 2 * nn[it] + 1];
        sp1_n[it] = sbn[2048 + j2n + nn[it]];
      }
      sp2_n[0] = sbn[3072 + (j2n >> 1) + 2 * q];
      sp2_n[1] = sbn[3072 + (j2n >> 1) + 2 * q + 1];
    }

    // ---- phase 1: 16 L2 nodes ----
    f32x4 acc[2][4];
    #pragma unroll
    for (int r = 0; r < 2; ++r)
      #pragma unroll
      for (int g = 0; g < 4; ++g) acc[r][g] = (f32x4){0.f, 0.f, 0.f, 0.f};
    #pragma unroll
    for (int K = 0; K < 4; ++K) {
      short8 a0 = *(const short8*)&Ag[cL][K * 32 + q * 8];
      short8 a1 = *(const short8*)&Ag[16 + cL][K * 32 + q * 8];
      #pragma unroll
      for (int g = 0; g < 4; ++g) {
        acc[0][g] = __builtin_amdgcn_mfma_f32_16x16x32_bf16(a0, bfr[g][K], acc[0][g], 0, 0, 0);
        acc[1][g] = __builtin_amdgcn_mfma_f32_16x16x32_bf16(a1, bfr[g][K], acc[1][g], 0, 0, 0);
      }
    }
    // issue next tile's long-latency gathers (h-row, c-values, symx values);
    // they land during phase 2 / next iteration (~2500 cy of cover).
    float clp_n[4], crp_n[4];
    float4 sx1_n[4], sx2_n[2];
    if (hasNext) {
      agv = *(const int4*)(gh8 + (size_t)gxr_n * H_ + coA);
      #pragma unroll
      for (int it = 0; it < 4; ++it) {
        clp_n[it] = gc[(size_t)g2l_n[it] * H_ + cc];
        crp_n[it] = gc[(size_t)g2r_n[it] * H_ + cc];
        sx1_n[it] = *(const float4*)(symx + (size_t)sp1_n[it] * 512 + cc * 4);
      }
      sx2_n[0] = *(const float4*)(symx + (size_t)sp2_n[0] * 512 + cc * 4);
      sx2_n[1] = *(const float4*)(symx + (size_t)sp2_n[1] * 512 + cc * 4);
    }

    #pragma unroll
    for (int r = 0; r < 2; ++r) {
      #pragma unroll
      for (int nd = 0; nd < 2; ++nd) {
        int it = r * 2 + nd;
        int n = 8 * r + 2 * q + nd;
        Gates gt = gate_combine(sx1[it],
            acc[r][0][2 * nd] + acc[r][0][2 * nd + 1],
            acc[r][1][2 * nd] + acc[r][1][2 * nd + 1],
            acc[r][2][2 * nd] + acc[r][2][2 * nd + 1],
            acc[r][3][2 * nd], acc[r][3][2 * nd + 1], clp[it], crp[it]);
        Bc[n][cc] = gt.cv;
        Bh[n][cc] = f2bf(gt.hv);
      }
    }
    bar_lds();                        // Bh/Bc visible

    // ---- phase 2: 8 L3 nodes ----
    f32x4 acc2[4];
    #pragma unroll
    for (int g = 0; g < 4; ++g) acc2[g] = (f32x4){0.f, 0.f, 0.f, 0.f};
    #pragma unroll
    for (int K = 0; K < 4; ++K) {
      short8 a0 = *(const short8*)&Bh[cL][K * 32 + q * 8];
      #pragma unroll
      for (int g = 0; g < 4; ++g)
        acc2[g] = __builtin_amdgcn_mfma_f32_16x16x32_bf16(a0, bfr[g][K], acc2[g], 0, 0, 0);
    }
    #pragma unroll
    for (int nd = 0; nd < 2; ++nd) {
      int n = 2 * q + nd;
      int G3 = tile * 8 + n;
      Gates gt = gate_combine(sx2[nd],
          acc2[0][2 * nd] + acc2[0][2 * nd + 1],
          acc2[1][2 * nd] + acc2[1][2 * nd + 1],
          acc2[2][2 * nd] + acc2[2][2 * nd + 1],
          acc2[3][2 * nd], acc2[3][2 * nd + 1],
          Bc[2 * n][cc], Bc[2 * n + 1][cc]);
      c_out[(size_t)G3 * H_ + cc] = gt.cv;
      h_out8[(size_t)G3 * H_ + cc] = f2bf(gt.hv);
    }
    // rotate prefetched values
    #pragma unroll
    for (int it = 0; it < 4; ++it) {
      clp[it] = clp_n[it]; crp[it] = crp_n[it]; sx1[it] = sx1_n[it];
    }
    sx2[0] = sx2_n[0]; sx2[1] = sx2_n[1];
  }
}

// ---- k_mid: levels 4-9 fused; 512 blocks, subtree-local, LDS ping-pong ----
__global__ void __launch_bounds__(512, 2) k_mid(
    const unsigned short* __restrict__ Wfrag, const float* __restrict__ symx,
    const int* __restrict__ symbols,
    const unsigned short* __restrict__ in_h8, const float* __restrict__ in_c,
    unsigned short* __restrict__ out_h8, float* __restrict__ out_c) {
  __shared__ __align__(16) unsigned short Ah0[64][136];
  __shared__ __align__(16) unsigned short Ah1[32][136];
  __shared__ float Cs0[64][128];
  __shared__ float Cs1[32][128];
  int t = threadIdx.x;
  int w = t >> 6, L = t & 63, q = L >> 4, cL = L & 15;
  int cc = 16 * w + cL;
  int blk = blockIdx.x;
  int b = blk >> 3, sub = blk & 7;
  size_t base3 = (size_t)blk * 64;

  #pragma unroll
  for (int i = 0; i < 2; ++i) {
    int fid = t + 512 * i;
    int row = fid >> 4, co = (fid & 15) * 8;
    *(int4*)&Ah0[row][co] = *(const int4*)(in_h8 + (base3 + row) * H_ + co);
  }
  #pragma unroll
  for (int i = 0; i < 4; ++i) {
    int fid = t + 512 * i;
    int row = fid >> 5, c4 = (fid & 31) << 2;
    *(float4*)&Cs0[row][c4] = *(const float4*)(in_c + (base3 + row) * H_ + c4);
  }
  __syncthreads();

  const short8* wf = (const short8*)Wfrag;
  int R = 64;
  #pragma unroll
  for (int lev = 0; lev < 6; ++lev) {
    const int l = 4 + lev;
    const int nodes = R >> 1;
    const int jb = b * (N_ - 1) + (N_ - (N_ >> (l - 1))) + ((sub * 32) >> lev);
    unsigned short (*Ard)[136] = (lev & 1) ? Ah1 : Ah0;
    unsigned short (*Awr)[136] = (lev & 1) ? Ah0 : Ah1;
    const float* crd = (lev & 1) ? &Cs1[0][0] : &Cs0[0][0];
    float* cwr = (lev & 1) ? &Cs0[0][0] : &Cs1[0][0];
    const int nchunk = (nodes + 15) >> 4;
    for (int c = 0; c < nchunk; ++c) {
      int spre[4];
      #pragma unroll
      for (int it = 0; it < 4; ++it) {
        int n = 16 * c + 8 * (it >> 1) + 2 * q + (it & 1);
        spre[it] = (n < nodes) ? symbols[jb + n] : 0;
      }
      f32x4 acc[2][4];
      #pragma unroll
      for (int r = 0; r < 2; ++r)
        #pragma unroll
        for (int g = 0; g < 4; ++g) acc[r][g] = (f32x4){0.f, 0.f, 0.f, 0.f};
      const bool useA1 = (2 * nodes - 32 * c) > 16;
      #pragma unroll
      for (int K = 0; K < 4; ++K) {
        short8 bfr[4];
        #pragma unroll
        for (int g = 0; g < 4; ++g) bfr[g] = wf[(size_t)((w + 8 * g) * 4 + K) * 64 + L];
        short8 a0 = *(const short8*)&Ard[32 * c + cL][K * 32 + q * 8];
        #pragma unroll
        for (int g = 0; g < 4; ++g)
          acc[0][g] = __builtin_amdgcn_mfma_f32_16x16x32_bf16(a0, bfr[g], acc[0][g], 0, 0, 0);
        if (useA1) {
          short8 a1 = *(const short8*)&Ard[32 * c + 16 + cL][K * 32 + q * 8];
          #pragma unroll
          for (int g = 0; g < 4; ++g)
            acc[1][g] = __builtin_amdgcn_mfma_f32_16x16x32_bf16(a1, bfr[g], acc[1][g], 0, 0, 0);
        }
      }
      #pragma unroll
      for (int r = 0; r < 2; ++r) {
        #pragma unroll
        for (int nd = 0; nd < 2; ++nd) {
          int it = r * 2 + nd;
          int n = 16 * c + 8 * r + 2 * q + nd;
          if (n < nodes) {
            float4 sx = *(const float4*)(symx + (size_t)spre[it] * 512 + cc * 4);
            Gates gt = gate_combine(sx,
                acc[r][0][2 * nd] + acc[r][0][2 * nd + 1],
                acc[r][1][2 * nd] + acc[r][1][2 * nd + 1],
                acc[r][2][2 * nd] + acc[r][2][2 * nd + 1],
                acc[r][3][2 * nd], acc[r][3][2 * nd + 1],
                crd[(size_t)(2 * n) * 128 + cc], crd[(size_t)(2 * n + 1) * 128 + cc]);
            if (lev == 5) {
              out_c[(size_t)blk * H_ + cc] = gt.cv;
              out_h8[(size_t)blk * H_ + cc] = f2bf(gt.hv);
            } else {
              cwr[(size_t)n * 128 + cc] = gt.cv;
              Awr[n][cc] = f2bf(gt.hv);
            }
          }
        }
      }
    }
    __syncthreads();
    R >>= 1;
  }
}

// ---- k_fin: levels 10-12 + fused projection (direct Wout rows); 64 blocks ----
__global__ void __launch_bounds__(512, 2) k_fin(
    const unsigned short* __restrict__ Wfrag, const float* __restrict__ symx,
    const int* __restrict__ symbols,
    const unsigned short* __restrict__ in_h8, const float* __restrict__ in_c,
    const float* __restrict__ Wout, const float* __restrict__ bout,
    float* __restrict__ out) {
  __shared__ __align__(16) unsigned short Ah0[8][136];
  __shared__ __align__(16) unsigned short Ah1[4][136];
  __shared__ float Cs0[8][128];
  __shared__ float Cs1[4][128];
  __shared__ float rootv[128];
  int t = threadIdx.x;
  int w = t >> 6, L = t & 63, q = L >> 4, cL = L & 15;
  int cc = 16 * w + cL;
  int b = blockIdx.x;

  if (t < 128) {
    int row = t >> 4, co = (t & 15) * 8;
    *(int4*)&Ah0[row][co] = *(const int4*)(in_h8 + (size_t)(b * 8 + row) * H_ + co);
  }
  if (t < 256) {
    int row = t >> 5, c4 = (t & 31) << 2;
    *(float4*)&Cs0[row][c4] = *(const float4*)(in_c + (size_t)(b * 8 + row) * H_ + c4);
  }
  __syncthreads();

  const short8* wf = (const short8*)Wfrag;
  int R = 8;
  #pragma unroll
  for (int lev = 0; lev < 3; ++lev) {
    const int l = 10 + lev;
    const int nodes = R >> 1;
    const int jb = b * (N_ - 1) + (N_ - (N_ >> (l - 1)));
    unsigned short (*Ard)[136] = (lev & 1) ? Ah1 : Ah0;
    unsigned short (*Awr)[136] = (lev & 1) ? Ah0 : Ah1;
    const float* crd = (lev & 1) ? &Cs1[0][0] : &Cs0[0][0];
    float* cwr = (lev & 1) ? &Cs0[0][0] : &Cs1[0][0];
    int spre[4];
    #pragma unroll
    for (int it = 0; it < 4; ++it) {
      int n = 8 * (it >> 1) + 2 * q + (it & 1);
      spre[it] = (n < nodes) ? symbols[jb + n] : 0;
    }
    f32x4 acc[4];
    #pragma unroll
    for (int g = 0; g < 4; ++g) acc[g] = (f32x4){0.f, 0.f, 0.f, 0.f};
    #pragma unroll
    for (int K = 0; K < 4; ++K) {
      short8 bfr[4];
      #pragma unroll
      for (int g = 0; g < 4; ++g) bfr[g] = wf[(size_t)((w + 8 * g) * 4 + K) * 64 + L];
      short8 a0 = *(const short8*)&Ard[cL & 7][K * 32 + q * 8];
      #pragma unroll
      for (int g = 0; g < 4; ++g)
        acc[g] = __builtin_amdgcn_mfma_f32_16x16x32_bf16(a0, bfr[g], acc[g], 0, 0, 0);
    }
    #pragma unroll
    for (int nd = 0; nd < 2; ++nd) {
      int it = nd;
      int n = 2 * q + nd;
      if (n < nodes) {
        float4 sx = *(const float4*)(symx + (size_t)spre[it] * 512 + cc * 4);
        Gates gt = gate_combine(sx,
            acc[0][2 * nd] + acc[0][2 * nd + 1],
            acc[1][2 * nd] + acc[1][2 * nd + 1],
            acc[2][2 * nd] + acc[2][2 * nd + 1],
            acc[3][2 * nd], acc[3][2 * nd + 1],
            crd[(size_t)(2 * n) * 128 + cc], crd[(size_t)(2 * n + 1) * 128 + cc]);
        if (lev == 2) {
          rootv[cc] = gt.hv;
        } else {
          cwr[(size_t)n * 128 + cc] = gt.cv;
          Awr[n][cc] = f2bf(gt.hv);
        }
      }
    }
    __syncthreads();
    R >>= 1;
  }
  if (t < 128) {
    float acc = bout[t];
    const float4* wr = (const float4*)(Wout + t * H_);
    #pragma unroll 4
    for (int k4 = 0; k4 < H_ / 4; ++k4) {
      float4 w4 = wr[k4];
      acc = fmaf(rootv[4 * k4], w4.x, acc); acc = fmaf(rootv[4 * k4 + 1], w4.y, acc);
      acc = fmaf(rootv[4 * k4 + 2], w4.z, acc); acc = fmaf(rootv[4 * k4 + 3], w4.w, acc);
    }
    out[(size_t)b * H_ + t] = acc;
  }
}

extern "C" void kernel_launch(void* const* d_in, const int* in_sizes, int n_in,
                              void* d_out, int out_size, void* d_ws, size_t ws_size,
                              hipStream_t stream) {
  const int* tokens    = (const int*)d_in[0];
  const int* symbols   = (const int*)d_in[1];
  const float* emb     = (const float*)d_in[2];
  const float* sym_emb = (const float*)d_in[3];
  const float* Wp  = (const float*)d_in[4];
  const float* bp  = (const float*)d_in[5];
  const float* Wi  = (const float*)d_in[6];
  const float* bi  = (const float*)d_in[7];
  const float* Ui  = (const float*)d_in[8];
  const float* Wf  = (const float*)d_in[9];
  const float* bf  = (const float*)d_in[10];
  const float* Uf  = (const float*)d_in[11];
  const float* Wo  = (const float*)d_in[12];
  const float* bo  = (const float*)d_in[13];
  const float* Uo  = (const float*)d_in[14];
  const float* Wu  = (const float*)d_in[15];
  const float* bu  = (const float*)d_in[16];
  const float* Uu  = (const float*)d_in[17];
  const float* Wout= (const float*)d_in[18];
  const float* bout= (const float*)d_in[19];

  // Workspace layout
  char* ws = (char*)d_ws;
  unsigned short* Wfrag   = (unsigned short*)(ws);                  // 131072
  float*          leaf_c  = (float*)(ws + 759040);                  // 10752
  float*          symx    = (float*)(ws + 769792);                  // 102400
  float*          P_leaf  = (float*)(ws + 872192);                  // 43008
  unsigned short* tab_h8  = (unsigned short*)(ws + 2001152UL);      // 5644800
  float*          tab_c   = (float*)(ws + 7645952UL);               // 11289600
  int*            idx1    = (int*)(ws + 18935552UL);                // 524288
  unsigned short* L3h8    = (unsigned short*)(ws + 19459840UL);     // 8388608
  float*          L3c     = (float*)(ws + 27848448UL);              // 16777216
  unsigned short* L9h8    = (unsigned short*)(ws + 44625664UL);     // 131072
  float*          L9c     = (float*)(ws + 44756736UL);              // 262144

  k_pre<<<16 + V_ + S_ + 256, 512, 0, stream>>>(
      Ui, Uo, Uu, Uf, Wi, Wo, Wu, Wf, Wp, emb, sym_emb,
      bp, bi, bo, bu, bf, tokens, symbols,
      Wfrag, leaf_c, symx, P_leaf, idx1);
  k_tabB<<<NTAB / 2, 256, 0, stream>>>(P_leaf, symx, leaf_c, tab_h8, tab_c);
  k_lvl23<<<512, 512, 0, stream>>>(Wfrag, symx, symbols, idx1, tab_h8, tab_c,
                                   L3h8, L3c);
  k_mid<<<512, 512, 0, stream>>>(Wfrag, symx, symbols, L3h8, L3c, L9h8, L9c);
  k_fin<<<B_, 512, 0, stream>>>(Wfrag, symx, symbols, L9h8, L9c, Wout, bout,
                                (float*)d_out);
}

// Round 12
// 196.664 us; speedup vs baseline: 1.1061x; 1.0029x over previous
//
#include <hip/hip_runtime.h>
#include <hip/hip_bf16.h>

typedef __attribute__((ext_vector_type(8))) short short8;
typedef __attribute__((ext_vector_type(4))) float f32x4;

static constexpr int B_ = 64;
static constexpr int N_ = 4096;
static constexpr int V_ = 21;
static constexpr int S_ = 50;
static constexpr int E_ = 64;
static constexpr int H_ = 128;
static constexpr int NPAIR = V_ * V_;   // 441
static constexpr int NTAB = NPAIR * S_; // 22050

__device__ __forceinline__ float rcp_(float x) { return __builtin_amdgcn_rcpf(x); }
__device__ __forceinline__ float sigm(float x) { return rcp_(1.0f + __expf(-x)); }
__device__ __forceinline__ float tanh_(float x) {
  float a = fabsf(x);
  float e = __expf(-2.0f * a);
  float t = (1.0f - e) * rcp_(1.0f + e);
  return x < 0.0f ? -t : t;
}
__device__ __forceinline__ unsigned short f2bf(float f) {
  __hip_bfloat16 b = __float2bfloat16(f);
  return *reinterpret_cast<unsigned short*>(&b);
}
__device__ __forceinline__ float bf2f(unsigned short u) {
  return __uint_as_float(((unsigned int)u) << 16);
}

struct Gates { float cv, hv; };
__device__ __forceinline__ Gates gate_combine(float4 sx,
    float i_p, float o_p, float u_p, float fl_p, float fr_p, float cl, float cr) {
  float gi = sigm(sx.x + i_p);
  float go = sigm(sx.y + o_p);
  float gu = tanh_(sx.z + u_p);
  float fl = sigm(sx.w + fl_p);
  float fr = sigm(sx.w + fr_p);
  float cv = fmaf(gi, gu, fmaf(fl, cl, fr * cr));
  Gates g; g.cv = cv; g.hv = go * tanh_(cv);
  return g;
}

// Raw barrier (no vmcnt drain): global prefetches stay in flight across it.
// lgkmcnt(0) retires our ds_writes before the barrier.
__device__ __forceinline__ void bar_lds() {
  asm volatile("s_waitcnt lgkmcnt(0)" ::: "memory");
  __builtin_amdgcn_s_barrier();
  asm volatile("" ::: "memory");
}

// ---- k_pre: Wfrag build + leaf tables + symx + idx1, all in one launch ----
__global__ void __launch_bounds__(512) k_pre(
    const float* __restrict__ Ui, const float* __restrict__ Uo,
    const float* __restrict__ Uu, const float* __restrict__ Uf,
    const float* __restrict__ Wi, const float* __restrict__ Wo,
    const float* __restrict__ Wu, const float* __restrict__ Wf,
    const float* __restrict__ Wp, const float* __restrict__ emb,
    const float* __restrict__ sym_emb,
    const float* __restrict__ bp, const float* __restrict__ bi,
    const float* __restrict__ bo, const float* __restrict__ bu,
    const float* __restrict__ bfv,
    const int* __restrict__ tokens, const int* __restrict__ symbols,
    unsigned short* __restrict__ Wfrag, float* __restrict__ leaf_c,
    float* __restrict__ symx, float* __restrict__ P_leaf,
    int* __restrict__ idx1) {
  __shared__ float x[128];
  __shared__ float zs[512];
  __shared__ float hl[128];
  int blk = blockIdx.x, t = threadIdx.x;
  if (blk < 16) {
    int idx = blk * 512 + t;  // 8192 frag entries
    int L = idx & 63;
    int K = (idx >> 6) & 3;
    int T = idx >> 8;
    int n = 16 * T + (L & 15);
    int k0 = 32 * K + ((L >> 4) << 3);
    int g = n >> 7, o = n & 127;
    const float* U = (g == 0) ? Ui : (g == 1) ? Uo : (g == 2) ? Uu : Uf;
    unsigned short out[8];
    #pragma unroll
    for (int j = 0; j < 8; ++j) out[j] = f2bf(U[o * 128 + k0 + j]);
    *(int4*)(Wfrag + (size_t)idx * 8) = *(int4*)out;
  } else if (blk < 16 + V_) {
    int v = blk - 16;
    if (t < 128) {
      float acc = bp[t];
      if (v != 0) {  // reference zeroes emb row 0
        const float4* wr = (const float4*)(Wp + t * E_);
        const float4* er = (const float4*)(emb + v * E_);
        #pragma unroll 4
        for (int e4 = 0; e4 < E_ / 4; ++e4) {
          float4 w4 = wr[e4], e4v = er[e4];
          acc = fmaf(e4v.x, w4.x, acc); acc = fmaf(e4v.y, w4.y, acc);
          acc = fmaf(e4v.z, w4.z, acc); acc = fmaf(e4v.w, w4.w, acc);
        }
      }
      x[t] = acc;
    }
    __syncthreads();
    if (t < 384) {  // cols 0..383 = i|o|u
      int g = t >> 7, o = t & 127;
      const float* bb = (g == 0) ? bi : (g == 1) ? bo : bu;
      const float* Wg = (g == 0) ? Wi : (g == 1) ? Wo : Wu;
      float z = bb[o];
      const float4* wr = (const float4*)(Wg + o * H_);
      #pragma unroll 4
      for (int k4 = 0; k4 < H_ / 4; ++k4) {
        float4 w4 = wr[k4];
        z = fmaf(x[4 * k4], w4.x, z); z = fmaf(x[4 * k4 + 1], w4.y, z);
        z = fmaf(x[4 * k4 + 2], w4.z, z); z = fmaf(x[4 * k4 + 3], w4.w, z);
      }
      zs[t] = z;
    }
    __syncthreads();
    if (t < 128) {
      float gi = sigm(zs[t]), go = sigm(zs[128 + t]), gu = tanh_(zs[256 + t]);
      float c = gi * gu;
      leaf_c[v * H_ + t] = c;
      unsigned short hb = f2bf(go * tanh_(c));
      hl[t] = bf2f(hb);
    }
    __syncthreads();
    {  // P_leaf row v: bf16-rounded h x fp32 U, all 512 cols (order i|o|u|f)
      int g = t >> 7, o = t & 127;
      const float* Ug = (g == 0) ? Ui : (g == 1) ? Uo : (g == 2) ? Uu : Uf;
      float z = 0.f;
      const float4* wr = (const float4*)(Ug + o * H_);
      #pragma unroll 4
      for (int k4 = 0; k4 < H_ / 4; ++k4) {
        float4 w4 = wr[k4];
        z = fmaf(hl[4 * k4], w4.x, z); z = fmaf(hl[4 * k4 + 1], w4.y, z);
        z = fmaf(hl[4 * k4 + 2], w4.z, z); z = fmaf(hl[4 * k4 + 3], w4.w, z);
      }
      P_leaf[(size_t)v * 512 + t] = z;
    }
  } else if (blk < 16 + V_ + S_) {
    int s = blk - 16 - V_;
    if (t < 128) {
      float acc = bp[t];
      const float4* wr = (const float4*)(Wp + t * E_);
      const float4* er = (const float4*)(sym_emb + s * E_);
      #pragma unroll 4
      for (int e4 = 0; e4 < E_ / 4; ++e4) {
        float4 w4 = wr[e4], e4v = er[e4];
        acc = fmaf(e4v.x, w4.x, acc); acc = fmaf(e4v.y, w4.y, acc);
        acc = fmaf(e4v.z, w4.z, acc); acc = fmaf(e4v.w, w4.w, acc);
      }
      x[t] = acc;
    }
    __syncthreads();
    {
      int g = t >> 7, o = t & 127;
      const float* bb = (g == 0) ? bi : (g == 1) ? bo : (g == 2) ? bu : bfv;
      const float* Wg = (g == 0) ? Wi : (g == 1) ? Wo : (g == 2) ? Wu : Wf;
      float z = bb[o];
      const float4* wr = (const float4*)(Wg + o * H_);
      #pragma unroll 4
      for (int k4 = 0; k4 < H_ / 4; ++k4) {
        float4 w4 = wr[k4];
        z = fmaf(x[4 * k4], w4.x, z); z = fmaf(x[4 * k4 + 1], w4.y, z);
        z = fmaf(x[4 * k4 + 2], w4.z, z); z = fmaf(x[4 * k4 + 3], w4.w, z);
      }
      zs[t] = z;
    }
    __syncthreads();
    if (t < 128) {
      float4 v4 = make_float4(zs[t], zs[128 + t], zs[256 + t], zs[384 + t]);
      *(float4*)(symx + (size_t)s * 512 + t * 4) = v4;
    }
  } else {
    int g = (blk - 16 - V_ - S_) * 512 + t;   // 131072 level-1 nodes
    int b = g >> 11, j = g & 2047;
    idx1[g] = (tokens[b * N_ + 2 * j] * V_ + tokens[b * N_ + 2 * j + 1]) * S_
              + symbols[b * (N_ - 1) + j];
  }
}

// ---- tabB: gate epilogue over 22050 rows (gathering from P_leaf) ----
__global__ void k_tabB(const float* __restrict__ P_leaf, const float* __restrict__ symx,
                       const float* __restrict__ leaf_c,
                       unsigned short* __restrict__ tab_h8, float* __restrict__ tab_c) {
  int blk = blockIdx.x, t = threadIdx.x;
  int row = blk * 2 + (t >> 7);
  int u = t & 127;
  int p = row / S_, s = row - p * S_;
  int tl = p / V_, tr = p - tl * V_;
  const float* Pl = P_leaf + (size_t)tl * 512;
  const float* Pr = P_leaf + (size_t)tr * 512;
  float4 sx = *(const float4*)(symx + (size_t)s * 512 + u * 4);
  Gates gt = gate_combine(sx,
      Pl[u] + Pr[u], Pl[128 + u] + Pr[128 + u], Pl[256 + u] + Pr[256 + u],
      Pl[384 + u], Pr[384 + u],
      leaf_c[tl * H_ + u], leaf_c[tr * H_ + u]);
  tab_c[(size_t)row * H_ + u] = gt.cv;
  tab_h8[(size_t)row * H_ + u] = f2bf(gt.hv);
}

// ---- fused levels 2+3: PERSISTENT blocks (grid 256 x CH 16), FULL pipeline
// (h-row, child-c, symx values prefetched one tile ahead), double-buffered Ag
// -> only 2 barriers per tile (Bh/Bc hazards ordered by the top-of-tile bar).
// NO launch_bounds min (r1/r7 spills); 1 block/CU -> regs are free (<256).
static constexpr int LVL23_CH = 16;
__global__ void __launch_bounds__(512) k_lvl23(
    const unsigned short* __restrict__ Wfrag, const float* __restrict__ symx,
    const int* __restrict__ symbols, const int* __restrict__ idx1,
    const unsigned short* __restrict__ gh8, const float* __restrict__ gc,
    unsigned short* __restrict__ h_out8, float* __restrict__ c_out) {
  __shared__ __align__(16) unsigned short Ag[2][32][136];
  __shared__ __align__(16) unsigned short Bh[16][136];
  __shared__ float Bc[16][132];
  const int t = threadIdx.x;
  const int w = t >> 6, L = t & 63, q = L >> 4, cL = L & 15;
  const int cc = 16 * w + cL;
  const int rowA = t >> 4, coA = (t & 15) * 8;

  // hoist weight fragments once per block
  const short8* wf = (const short8*)Wfrag;
  short8 bfr[4][4];
  #pragma unroll
  for (int K = 0; K < 4; ++K)
    #pragma unroll
    for (int g = 0; g < 4; ++g)
      bfr[g][K] = wf[(size_t)((w + 8 * g) * 4 + K) * 64 + L];

  const int t0 = blockIdx.x * LVL23_CH;

  int nn[4];
  #pragma unroll
  for (int it = 0; it < 4; ++it) nn[it] = 8 * (it >> 1) + 2 * q + (it & 1);

  // ---- prologue: fully prefetch tile t0 (h-row, c-values, symx values) ----
  int4 agv;
  float clp[4], crp[4];
  float4 sx1[4], sx2[2];
  {
    int gxr = idx1[t0 * 32 + rowA];
    agv = *(const int4*)(gh8 + (size_t)gxr * H_ + coA);
    const int* sb = symbols + (size_t)(t0 >> 6) * (N_ - 1);
    const int j20 = (t0 & 63) * 16;
    #pragma unroll
    for (int it = 0; it < 4; ++it) {
      int g2l = idx1[t0 * 32 + 2 * nn[it]];
      int g2r = idx1[t0 * 32 + 2 * nn[it] + 1];
      clp[it] = gc[(size_t)g2l * H_ + cc];
      crp[it] = gc[(size_t)g2r * H_ + cc];
      int sp = sb[2048 + j20 + nn[it]];
      sx1[it] = *(const float4*)(symx + (size_t)sp * 512 + cc * 4);
    }
    #pragma unroll
    for (int nd = 0; nd < 2; ++nd) {
      int sp = sb[3072 + (j20 >> 1) + 2 * q + nd];
      sx2[nd] = *(const float4*)(symx + (size_t)sp * 512 + cc * 4);
    }
  }

  for (int k = 0; k < LVL23_CH; ++k) {
    const int tile = t0 + k;
    const int buf = k & 1;
    const bool hasNext = (k + 1 < LVL23_CH);

    // double-buffered Ag: readers of Ag[buf] finished two tiles ago (ordered
    // by the intervening top-of-tile barriers) -> no pre-write barrier needed.
    *(int4*)&Ag[buf][rowA][coA] = agv;
    bar_lds();                        // Ag[buf] visible; also orders Bh/Bc reuse

    // next-tile index loads (L2-hot); value gathers issued mid-phase-1
    int gxr_n = 0, g2l_n[4], g2r_n[4], sp1_n[4], sp2_n[2];
    if (hasNext) {
      const int tn = tile + 1;
      const int* sbn = symbols + (size_t)(tn >> 6) * (N_ - 1);
      const int j2n = (tn & 63) * 16;
      gxr_n = idx1[tn * 32 + rowA];
      #pragma unroll
      for (int it = 0; it < 4; ++it) {
        g2l_n[it] = idx1[tn * 32 + 2 * nn[it]];
        g2r_n[it] = idx1[tn * 32 + 2 * nn[it] + 1];
        sp1_n[it] = sbn[2048 + j2n + nn[it]];
      }
      sp2_n[0] = sbn[3072 + (j2n >> 1) + 2 * q];
      sp2_n[1] = sbn[3072 + (j2n >> 1) + 2 * q + 1];
    }

    // ---- phase 1: 16 L2 nodes ----
    f32x4 acc[2][4];
    #pragma unroll
    for (int r = 0; r < 2; ++r)
      #pragma unroll
      for (int g = 0; g < 4; ++g) acc[r][g] = (f32x4){0.f, 0.f, 0.f, 0.f};
    #pragma unroll
    for (int K = 0; K < 4; ++K) {
      short8 a0 = *(const short8*)&Ag[buf][cL][K * 32 + q * 8];
      short8 a1 = *(const short8*)&Ag[buf][16 + cL][K * 32 + q * 8];
      #pragma unroll
      for (int g = 0; g < 4; ++g) {
        acc[0][g] = __builtin_amdgcn_mfma_f32_16x16x32_bf16(a0, bfr[g][K], acc[0][g], 0, 0, 0);
        acc[1][g] = __builtin_amdgcn_mfma_f32_16x16x32_bf16(a1, bfr[g][K], acc[1][g], 0, 0, 0);
      }
    }
    // issue next tile's long-latency gathers (h-row, c-values, symx values);
    // they land during phase 2 / next iteration (~2500 cy of cover).
    float clp_n[4], crp_n[4];
    float4 sx1_n[4], sx2_n[2];
    if (hasNext) {
      agv = *(const int4*)(gh8 + (size_t)gxr_n * H_ + coA);
      #pragma unroll
      for (int it = 0; it < 4; ++it) {
        clp_n[it] = gc[(size_t)g2l_n[it] * H_ + cc];
        crp_n[it] = gc[(size_t)g2r_n[it] * H_ + cc];
        sx1_n[it] = *(const float4*)(symx + (size_t)sp1_n[it] * 512 + cc * 4);
      }
      sx2_n[0] = *(const float4*)(symx + (size_t)sp2_n[0] * 512 + cc * 4);
      sx2_n[1] = *(const float4*)(symx + (size_t)sp2_n[1] * 512 + cc * 4);
    }

    #pragma unroll
    for (int r = 0; r < 2; ++r) {
      #pragma unroll
      for (int nd = 0; nd < 2; ++nd) {
        int it = r * 2 + nd;
        int n = 8 * r + 2 * q + nd;
        Gates gt = gate_combine(sx1[it],
            acc[r][0][2 * nd] + acc[r][0][2 * nd + 1],
            acc[r][1][2 * nd] + acc[r][1][2 * nd + 1],
            acc[r][2][2 * nd] + acc[r][2][2 * nd + 1],
            acc[r][3][2 * nd], acc[r][3][2 * nd + 1], clp[it], crp[it]);
        Bc[n][cc] = gt.cv;
        Bh[n][cc] = f2bf(gt.hv);
      }
    }
    bar_lds();                        // Bh/Bc visible

    // ---- phase 2: 8 L3 nodes ----
    f32x4 acc2[4];
    #pragma unroll
    for (int g = 0; g < 4; ++g) acc2[g] = (f32x4){0.f, 0.f, 0.f, 0.f};
    #pragma unroll
    for (int K = 0; K < 4; ++K) {
      short8 a0 = *(const short8*)&Bh[cL][K * 32 + q * 8];
      #pragma unroll
      for (int g = 0; g < 4; ++g)
        acc2[g] = __builtin_amdgcn_mfma_f32_16x16x32_bf16(a0, bfr[g][K], acc2[g], 0, 0, 0);
    }
    #pragma unroll
    for (int nd = 0; nd < 2; ++nd) {
      int n = 2 * q + nd;
      int G3 = tile * 8 + n;
      Gates gt = gate_combine(sx2[nd],
          acc2[0][2 * nd] + acc2[0][2 * nd + 1],
          acc2[1][2 * nd] + acc2[1][2 * nd + 1],
          acc2[2][2 * nd] + acc2[2][2 * nd + 1],
          acc2[3][2 * nd], acc2[3][2 * nd + 1],
          Bc[2 * n][cc], Bc[2 * n + 1][cc]);
      c_out[(size_t)G3 * H_ + cc] = gt.cv;
      h_out8[(size_t)G3 * H_ + cc] = f2bf(gt.hv);
    }
    // rotate prefetched values
    #pragma unroll
    for (int it = 0; it < 4; ++it) {
      clp[it] = clp_n[it]; crp[it] = crp_n[it]; sx1[it] = sx1_n[it];
    }
    sx2[0] = sx2_n[0]; sx2[1] = sx2_n[1];
  }
}

// ---- k_mid: levels 4-9 fused; 512 blocks, subtree-local, LDS ping-pong ----
__global__ void __launch_bounds__(512, 2) k_mid(
    const unsigned short* __restrict__ Wfrag, const float* __restrict__ symx,
    const int* __restrict__ symbols,
    const unsigned short* __restrict__ in_h8, const float* __restrict__ in_c,
    unsigned short* __restrict__ out_h8, float* __restrict__ out_c) {
  __shared__ __align__(16) unsigned short Ah0[64][136];
  __shared__ __align__(16) unsigned short Ah1[32][136];
  __shared__ float Cs0[64][128];
  __shared__ float Cs1[32][128];
  int t = threadIdx.x;
  int w = t >> 6, L = t & 63, q = L >> 4, cL = L & 15;
  int cc = 16 * w + cL;
  int blk = blockIdx.x;
  int b = blk >> 3, sub = blk & 7;
  size_t base3 = (size_t)blk * 64;

  #pragma unroll
  for (int i = 0; i < 2; ++i) {
    int fid = t + 512 * i;
    int row = fid >> 4, co = (fid & 15) * 8;
    *(int4*)&Ah0[row][co] = *(const int4*)(in_h8 + (base3 + row) * H_ + co);
  }
  #pragma unroll
  for (int i = 0; i < 4; ++i) {
    int fid = t + 512 * i;
    int row = fid >> 5, c4 = (fid & 31) << 2;
    *(float4*)&Cs0[row][c4] = *(const float4*)(in_c + (base3 + row) * H_ + c4);
  }
  __syncthreads();

  const short8* wf = (const short8*)Wfrag;
  int R = 64;
  #pragma unroll
  for (int lev = 0; lev < 6; ++lev) {
    const int l = 4 + lev;
    const int nodes = R >> 1;
    const int jb = b * (N_ - 1) + (N_ - (N_ >> (l - 1))) + ((sub * 32) >> lev);
    unsigned short (*Ard)[136] = (lev & 1) ? Ah1 : Ah0;
    unsigned short (*Awr)[136] = (lev & 1) ? Ah0 : Ah1;
    const float* crd = (lev & 1) ? &Cs1[0][0] : &Cs0[0][0];
    float* cwr = (lev & 1) ? &Cs0[0][0] : &Cs1[0][0];
    const int nchunk = (nodes + 15) >> 4;
    for (int c = 0; c < nchunk; ++c) {
      int spre[4];
      #pragma unroll
      for (int it = 0; it < 4; ++it) {
        int n = 16 * c + 8 * (it >> 1) + 2 * q + (it & 1);
        spre[it] = (n < nodes) ? symbols[jb + n] : 0;
      }
      f32x4 acc[2][4];
      #pragma unroll
      for (int r = 0; r < 2; ++r)
        #pragma unroll
        for (int g = 0; g < 4; ++g) acc[r][g] = (f32x4){0.f, 0.f, 0.f, 0.f};
      const bool useA1 = (2 * nodes - 32 * c) > 16;
      #pragma unroll
      for (int K = 0; K < 4; ++K) {
        short8 bfr[4];
        #pragma unroll
        for (int g = 0; g < 4; ++g) bfr[g] = wf[(size_t)((w + 8 * g) * 4 + K) * 64 + L];
        short8 a0 = *(const short8*)&Ard[32 * c + cL][K * 32 + q * 8];
        #pragma unroll
        for (int g = 0; g < 4; ++g)
          acc[0][g] = __builtin_amdgcn_mfma_f32_16x16x32_bf16(a0, bfr[g], acc[0][g], 0, 0, 0);
        if (useA1) {
          short8 a1 = *(const short8*)&Ard[32 * c + 16 + cL][K * 32 + q * 8];
          #pragma unroll
          for (int g = 0; g < 4; ++g)
            acc[1][g] = __builtin_amdgcn_mfma_f32_16x16x32_bf16(a1, bfr[g], acc[1][g], 0, 0, 0);
        }
      }
      #pragma unroll
      for (int r = 0; r < 2; ++r) {
        #pragma unroll
        for (int nd = 0; nd < 2; ++nd) {
          int it = r * 2 + nd;
          int n = 16 * c + 8 * r + 2 * q + nd;
          if (n < nodes) {
            float4 sx = *(const float4*)(symx + (size_t)spre[it] * 512 + cc * 4);
            Gates gt = gate_combine(sx,
                acc[r][0][2 * nd] + acc[r][0][2 * nd + 1],
                acc[r][1][2 * nd] + acc[r][1][2 * nd + 1],
                acc[r][2][2 * nd] + acc[r][2][2 * nd + 1],
                acc[r][3][2 * nd], acc[r][3][2 * nd + 1],
                crd[(size_t)(2 * n) * 128 + cc], crd[(size_t)(2 * n + 1) * 128 + cc]);
            if (lev == 5) {
              out_c[(size_t)blk * H_ + cc] = gt.cv;
              out_h8[(size_t)blk * H_ + cc] = f2bf(gt.hv);
            } else {
              cwr[(size_t)n * 128 + cc] = gt.cv;
              Awr[n][cc] = f2bf(gt.hv);
            }
          }
        }
      }
    }
    __syncthreads();
    R >>= 1;
  }
}

// ---- k_fin: levels 10-12 + fused projection (direct Wout rows); 64 blocks ----
__global__ void __launch_bounds__(512, 2) k_fin(
    const unsigned short* __restrict__ Wfrag, const float* __restrict__ symx,
    const int* __restrict__ symbols,
    const unsigned short* __restrict__ in_h8, const float* __restrict__ in_c,
    const float* __restrict__ Wout, const float* __restrict__ bout,
    float* __restrict__ out) {
  __shared__ __align__(16) unsigned short Ah0[8][136];
  __shared__ __align__(16) unsigned short Ah1[4][136];
  __shared__ float Cs0[8][128];
  __shared__ float Cs1[4][128];
  __shared__ float rootv[128];
  int t = threadIdx.x;
  int w = t >> 6, L = t & 63, q = L >> 4, cL = L & 15;
  int cc = 16 * w + cL;
  int b = blockIdx.x;

  if (t < 128) {
    int row = t >> 4, co = (t & 15) * 8;
    *(int4*)&Ah0[row][co] = *(const int4*)(in_h8 + (size_t)(b * 8 + row) * H_ + co);
  }
  if (t < 256) {
    int row = t >> 5, c4 = (t & 31) << 2;
    *(float4*)&Cs0[row][c4] = *(const float4*)(in_c + (size_t)(b * 8 + row) * H_ + c4);
  }
  __syncthreads();

  const short8* wf = (const short8*)Wfrag;
  int R = 8;
  #pragma unroll
  for (int lev = 0; lev < 3; ++lev) {
    const int l = 10 + lev;
    const int nodes = R >> 1;
    const int jb = b * (N_ - 1) + (N_ - (N_ >> (l - 1)));
    unsigned short (*Ard)[136] = (lev & 1) ? Ah1 : Ah0;
    unsigned short (*Awr)[136] = (lev & 1) ? Ah0 : Ah1;
    const float* crd = (lev & 1) ? &Cs1[0][0] : &Cs0[0][0];
    float* cwr = (lev & 1) ? &Cs0[0][0] : &Cs1[0][0];
    int spre[4];
    #pragma unroll
    for (int it = 0; it < 4; ++it) {
      int n = 8 * (it >> 1) + 2 * q + (it & 1);
      spre[it] = (n < nodes) ? symbols[jb + n] : 0;
    }
    f32x4 acc[4];
    #pragma unroll
    for (int g = 0; g < 4; ++g) acc[g] = (f32x4){0.f, 0.f, 0.f, 0.f};
    #pragma unroll
    for (int K = 0; K < 4; ++K) {
      short8 bfr[4];
      #pragma unroll
      for (int g = 0; g < 4; ++g) bfr[g] = wf[(size_t)((w + 8 * g) * 4 + K) * 64 + L];
      short8 a0 = *(const short8*)&Ard[cL & 7][K * 32 + q * 8];
      #pragma unroll
      for (int g = 0; g < 4; ++g)
        acc[g] = __builtin_amdgcn_mfma_f32_16x16x32_bf16(a0, bfr[g], acc[g], 0, 0, 0);
    }
    #pragma unroll
    for (int nd = 0; nd < 2; ++nd) {
      int it = nd;
      int n = 2 * q + nd;
      if (n < nodes) {
        float4 sx = *(const float4*)(symx + (size_t)spre[it] * 512 + cc * 4);
        Gates gt = gate_combine(sx,
            acc[0][2 * nd] + acc[0][2 * nd + 1],
            acc[1][2 * nd] + acc[1][2 * nd + 1],
            acc[2][2 * nd] + acc[2][2 * nd + 1],
            acc[3][2 * nd], acc[3][2 * nd + 1],
            crd[(size_t)(2 * n) * 128 + cc], crd[(size_t)(2 * n + 1) * 128 + cc]);
        if (lev == 2) {
          rootv[cc] = gt.hv;
        } else {
          cwr[(size_t)n * 128 + cc] = gt.cv;
          Awr[n][cc] = f2bf(gt.hv);
        }
      }
    }
    __syncthreads();
    R >>= 1;
  }
  if (t < 128) {
    float acc = bout[t];
    const float4* wr = (const float4*)(Wout + t * H_);
    #pragma unroll 4
    for (int k4 = 0; k4 < H_ / 4; ++k4) {
      float4 w4 = wr[k4];
      acc = fmaf(rootv[4 * k4], w4.x, acc); acc = fmaf(rootv[4 * k4 + 1], w4.y, acc);
      acc = fmaf(rootv[4 * k4 + 2], w4.z, acc); acc = fmaf(rootv[4 * k4 + 3], w4.w, acc);
    }
    out[(size_t)b * H_ + t] = acc;
  }
}

extern "C" void kernel_launch(void* const* d_in, const int* in_sizes, int n_in,
                              void* d_out, int out_size, void* d_ws, size_t ws_size,
                              hipStream_t stream) {
  const int* tokens    = (const int*)d_in[0];
  const int* symbols   = (const int*)d_in[1];
  const float* emb     = (const float*)d_in[2];
  const float* sym_emb = (const float*)d_in[3];
  const float* Wp  = (const float*)d_in[4];
  const float* bp  = (const float*)d_in[5];
  const float* Wi  = (const float*)d_in[6];
  const float* bi  = (const float*)d_in[7];
  const float* Ui  = (const float*)d_in[8];
  const float* Wf  = (const float*)d_in[9];
  const float* bf  = (const float*)d_in[10];
  const float* Uf  = (const float*)d_in[11];
  const float* Wo  = (const float*)d_in[12];
  const float* bo  = (const float*)d_in[13];
  const float* Uo  = (const float*)d_in[14];
  const float* Wu  = (const float*)d_in[15];
  const float* bu  = (const float*)d_in[16];
  const float* Uu  = (const float*)d_in[17];
  const float* Wout= (const float*)d_in[18];
  const float* bout= (const float*)d_in[19];

  // Workspace layout
  char* ws = (char*)d_ws;
  unsigned short* Wfrag   = (unsigned short*)(ws);                  // 131072
  float*          leaf_c  = (float*)(ws + 759040);                  // 10752
  float*          symx    = (float*)(ws + 769792);                  // 102400
  float*          P_leaf  = (float*)(ws + 872192);                  // 43008
  unsigned short* tab_h8  = (unsigned short*)(ws + 2001152UL);      // 5644800
  float*          tab_c   = (float*)(ws + 7645952UL);               // 11289600
  int*            idx1    = (int*)(ws + 18935552UL);                // 524288
  unsigned short* L3h8    = (unsigned short*)(ws + 19459840UL);     // 8388608
  float*          L3c     = (float*)(ws + 27848448UL);              // 16777216
  unsigned short* L9h8    = (unsigned short*)(ws + 44625664UL);     // 131072
  float*          L9c     = (float*)(ws + 44756736UL);              // 262144

  k_pre<<<16 + V_ + S_ + 256, 512, 0, stream>>>(
      Ui, Uo, Uu, Uf, Wi, Wo, Wu, Wf, Wp, emb, sym_emb,
      bp, bi, bo, bu, bf, tokens, symbols,
      Wfrag, leaf_c, symx, P_leaf, idx1);
  k_tabB<<<NTAB / 2, 256, 0, stream>>>(P_leaf, symx, leaf_c, tab_h8, tab_c);
  k_lvl23<<<256, 512, 0, stream>>>(Wfrag, symx, symbols, idx1, tab_h8, tab_c,
                                   L3h8, L3c);
  k_mid<<<512, 512, 0, stream>>>(Wfrag, symx, symbols, L3h8, L3c, L9h8, L9c);
  k_fin<<<B_, 512, 0, stream>>>(Wfrag, symx, symbols, L9h8, L9c, Wout, bout,
                                (float*)d_out);
}

// Round 13
// 191.985 us; speedup vs baseline: 1.1330x; 1.0244x over previous
//
#include <hip/hip_runtime.h>
#include <hip/hip_bf16.h>

typedef __attribute__((ext_vector_type(8))) short short8;
typedef __attribute__((ext_vector_type(4))) float f32x4;

static constexpr int B_ = 64;
static constexpr int N_ = 4096;
static constexpr int V_ = 21;
static constexpr int S_ = 50;
static constexpr int E_ = 64;
static constexpr int H_ = 128;
static constexpr int NPAIR = V_ * V_;   // 441
static constexpr int NTAB = NPAIR * S_; // 22050

__device__ __forceinline__ float rcp_(float x) { return __builtin_amdgcn_rcpf(x); }
__device__ __forceinline__ float sigm(float x) { return rcp_(1.0f + __expf(-x)); }
__device__ __forceinline__ float tanh_(float x) {
  float a = fabsf(x);
  float e = __expf(-2.0f * a);
  float t = (1.0f - e) * rcp_(1.0f + e);
  return x < 0.0f ? -t : t;
}
__device__ __forceinline__ unsigned short f2bf(float f) {
  __hip_bfloat16 b = __float2bfloat16(f);
  return *reinterpret_cast<unsigned short*>(&b);
}
__device__ __forceinline__ float bf2f(unsigned short u) {
  return __uint_as_float(((unsigned int)u) << 16);
}

struct Gates { float cv, hv; };
__device__ __forceinline__ Gates gate_combine(float4 sx,
    float i_p, float o_p, float u_p, float fl_p, float fr_p, float cl, float cr) {
  float gi = sigm(sx.x + i_p);
  float go = sigm(sx.y + o_p);
  float gu = tanh_(sx.z + u_p);
  float fl = sigm(sx.w + fl_p);
  float fr = sigm(sx.w + fr_p);
  float cv = fmaf(gi, gu, fmaf(fl, cl, fr * cr));
  Gates g; g.cv = cv; g.hv = go * tanh_(cv);
  return g;
}

// Raw barrier (no vmcnt drain): global prefetches stay in flight across it.
// lgkmcnt(0) retires our ds_writes before the barrier.
__device__ __forceinline__ void bar_lds() {
  asm volatile("s_waitcnt lgkmcnt(0)" ::: "memory");
  __builtin_amdgcn_s_barrier();
  asm volatile("" ::: "memory");
}

// ---- k_pre: Wfrag build + leaf tables + symx + idx1, all in one launch ----
__global__ void __launch_bounds__(512) k_pre(
    const float* __restrict__ Ui, const float* __restrict__ Uo,
    const float* __restrict__ Uu, const float* __restrict__ Uf,
    const float* __restrict__ Wi, const float* __restrict__ Wo,
    const float* __restrict__ Wu, const float* __restrict__ Wf,
    const float* __restrict__ Wp, const float* __restrict__ emb,
    const float* __restrict__ sym_emb,
    const float* __restrict__ bp, const float* __restrict__ bi,
    const float* __restrict__ bo, const float* __restrict__ bu,
    const float* __restrict__ bfv,
    const int* __restrict__ tokens, const int* __restrict__ symbols,
    unsigned short* __restrict__ Wfrag, float* __restrict__ leaf_c,
    float* __restrict__ symx, float* __restrict__ P_leaf,
    int* __restrict__ idx1) {
  __shared__ float x[128];
  __shared__ float zs[512];
  __shared__ float hl[128];
  int blk = blockIdx.x, t = threadIdx.x;
  if (blk < 16) {
    int idx = blk * 512 + t;  // 8192 frag entries
    int L = idx & 63;
    int K = (idx >> 6) & 3;
    int T = idx >> 8;
    int n = 16 * T + (L & 15);
    int k0 = 32 * K + ((L >> 4) << 3);
    int g = n >> 7, o = n & 127;
    const float* U = (g == 0) ? Ui : (g == 1) ? Uo : (g == 2) ? Uu : Uf;
    unsigned short out[8];
    #pragma unroll
    for (int j = 0; j < 8; ++j) out[j] = f2bf(U[o * 128 + k0 + j]);
    *(int4*)(Wfrag + (size_t)idx * 8) = *(int4*)out;
  } else if (blk < 16 + V_) {
    int v = blk - 16;
    if (t < 128) {
      float acc = bp[t];
      if (v != 0) {  // reference zeroes emb row 0
        const float4* wr = (const float4*)(Wp + t * E_);
        const float4* er = (const float4*)(emb + v * E_);
        #pragma unroll 4
        for (int e4 = 0; e4 < E_ / 4; ++e4) {
          float4 w4 = wr[e4], e4v = er[e4];
          acc = fmaf(e4v.x, w4.x, acc); acc = fmaf(e4v.y, w4.y, acc);
          acc = fmaf(e4v.z, w4.z, acc); acc = fmaf(e4v.w, w4.w, acc);
        }
      }
      x[t] = acc;
    }
    __syncthreads();
    if (t < 384) {  // cols 0..383 = i|o|u
      int g = t >> 7, o = t & 127;
      const float* bb = (g == 0) ? bi : (g == 1) ? bo : bu;
      const float* Wg = (g == 0) ? Wi : (g == 1) ? Wo : Wu;
      float z = bb[o];
      const float4* wr = (const float4*)(Wg + o * H_);
      #pragma unroll 4
      for (int k4 = 0; k4 < H_ / 4; ++k4) {
        float4 w4 = wr[k4];
        z = fmaf(x[4 * k4], w4.x, z); z = fmaf(x[4 * k4 + 1], w4.y, z);
        z = fmaf(x[4 * k4 + 2], w4.z, z); z = fmaf(x[4 * k4 + 3], w4.w, z);
      }
      zs[t] = z;
    }
    __syncthreads();
    if (t < 128) {
      float gi = sigm(zs[t]), go = sigm(zs[128 + t]), gu = tanh_(zs[256 + t]);
      float c = gi * gu;
      leaf_c[v * H_ + t] = c;
      unsigned short hb = f2bf(go * tanh_(c));
      hl[t] = bf2f(hb);
    }
    __syncthreads();
    {  // P_leaf row v: bf16-rounded h x fp32 U, all 512 cols (order i|o|u|f)
      int g = t >> 7, o = t & 127;
      const float* Ug = (g == 0) ? Ui : (g == 1) ? Uo : (g == 2) ? Uu : Uf;
      float z = 0.f;
      const float4* wr = (const float4*)(Ug + o * H_);
      #pragma unroll 4
      for (int k4 = 0; k4 < H_ / 4; ++k4) {
        float4 w4 = wr[k4];
        z = fmaf(hl[4 * k4], w4.x, z); z = fmaf(hl[4 * k4 + 1], w4.y, z);
        z = fmaf(hl[4 * k4 + 2], w4.z, z); z = fmaf(hl[4 * k4 + 3], w4.w, z);
      }
      P_leaf[(size_t)v * 512 + t] = z;
    }
  } else if (blk < 16 + V_ + S_) {
    int s = blk - 16 - V_;
    if (t < 128) {
      float acc = bp[t];
      const float4* wr = (const float4*)(Wp + t * E_);
      const float4* er = (const float4*)(sym_emb + s * E_);
      #pragma unroll 4
      for (int e4 = 0; e4 < E_ / 4; ++e4) {
        float4 w4 = wr[e4], e4v = er[e4];
        acc = fmaf(e4v.x, w4.x, acc); acc = fmaf(e4v.y, w4.y, acc);
        acc = fmaf(e4v.z, w4.z, acc); acc = fmaf(e4v.w, w4.w, acc);
      }
      x[t] = acc;
    }
    __syncthreads();
    {
      int g = t >> 7, o = t & 127;
      const float* bb = (g == 0) ? bi : (g == 1) ? bo : (g == 2) ? bu : bfv;
      const float* Wg = (g == 0) ? Wi : (g == 1) ? Wo : (g == 2) ? Wu : Wf;
      float z = bb[o];
      const float4* wr = (const float4*)(Wg + o * H_);
      #pragma unroll 4
      for (int k4 = 0; k4 < H_ / 4; ++k4) {
        float4 w4 = wr[k4];
        z = fmaf(x[4 * k4], w4.x, z); z = fmaf(x[4 * k4 + 1], w4.y, z);
        z = fmaf(x[4 * k4 + 2], w4.z, z); z = fmaf(x[4 * k4 + 3], w4.w, z);
      }
      zs[t] = z;
    }
    __syncthreads();
    if (t < 128) {
      float4 v4 = make_float4(zs[t], zs[128 + t], zs[256 + t], zs[384 + t]);
      *(float4*)(symx + (size_t)s * 512 + t * 4) = v4;
    }
  } else {
    int g = (blk - 16 - V_ - S_) * 512 + t;   // 131072 level-1 nodes
    int b = g >> 11, j = g & 2047;
    idx1[g] = (tokens[b * N_ + 2 * j] * V_ + tokens[b * N_ + 2 * j + 1]) * S_
              + symbols[b * (N_ - 1) + j];
  }
}

// ---- tabB: gate epilogue over 22050 rows (gathering from P_leaf) ----
__global__ void k_tabB(const float* __restrict__ P_leaf, const float* __restrict__ symx,
                       const float* __restrict__ leaf_c,
                       unsigned short* __restrict__ tab_h8, float* __restrict__ tab_c) {
  int blk = blockIdx.x, t = threadIdx.x;
  int row = blk * 2 + (t >> 7);
  int u = t & 127;
  int p = row / S_, s = row - p * S_;
  int tl = p / V_, tr = p - tl * V_;
  const float* Pl = P_leaf + (size_t)tl * 512;
  const float* Pr = P_leaf + (size_t)tr * 512;
  float4 sx = *(const float4*)(symx + (size_t)s * 512 + u * 4);
  Gates gt = gate_combine(sx,
      Pl[u] + Pr[u], Pl[128 + u] + Pr[128 + u], Pl[256 + u] + Pr[256 + u],
      Pl[384 + u], Pr[384 + u],
      leaf_c[tl * H_ + u], leaf_c[tr * H_ + u]);
  tab_c[(size_t)row * H_ + u] = gt.cv;
  tab_h8[(size_t)row * H_ + u] = f2bf(gt.hv);
}

// ---- fused levels 2+3: PERSISTENT blocks (grid 256 x CH 16), FULL pipeline
// (h-row, child-c, symx values prefetched one tile ahead), double-buffered Ag
// -> only 2 barriers per tile. NO launch_bounds min (r1/r7 spills).
static constexpr int LVL23_CH = 16;
__global__ void __launch_bounds__(512) k_lvl23(
    const unsigned short* __restrict__ Wfrag, const float* __restrict__ symx,
    const int* __restrict__ symbols, const int* __restrict__ idx1,
    const unsigned short* __restrict__ gh8, const float* __restrict__ gc,
    unsigned short* __restrict__ h_out8, float* __restrict__ c_out) {
  __shared__ __align__(16) unsigned short Ag[2][32][136];
  __shared__ __align__(16) unsigned short Bh[16][136];
  __shared__ float Bc[16][132];
  const int t = threadIdx.x;
  const int w = t >> 6, L = t & 63, q = L >> 4, cL = L & 15;
  const int cc = 16 * w + cL;
  const int rowA = t >> 4, coA = (t & 15) * 8;

  // hoist weight fragments once per block
  const short8* wf = (const short8*)Wfrag;
  short8 bfr[4][4];
  #pragma unroll
  for (int K = 0; K < 4; ++K)
    #pragma unroll
    for (int g = 0; g < 4; ++g)
      bfr[g][K] = wf[(size_t)((w + 8 * g) * 4 + K) * 64 + L];

  const int t0 = blockIdx.x * LVL23_CH;

  int nn[4];
  #pragma unroll
  for (int it = 0; it < 4; ++it) nn[it] = 8 * (it >> 1) + 2 * q + (it & 1);

  // ---- prologue: fully prefetch tile t0 (h-row, c-values, symx values) ----
  int4 agv;
  float clp[4], crp[4];
  float4 sx1[4], sx2[2];
  {
    int gxr = idx1[t0 * 32 + rowA];
    agv = *(const int4*)(gh8 + (size_t)gxr * H_ + coA);
    const int* sb = symbols + (size_t)(t0 >> 6) * (N_ - 1);
    const int j20 = (t0 & 63) * 16;
    #pragma unroll
    for (int it = 0; it < 4; ++it) {
      int g2l = idx1[t0 * 32 + 2 * nn[it]];
      int g2r = idx1[t0 * 32 + 2 * nn[it] + 1];
      clp[it] = gc[(size_t)g2l * H_ + cc];
      crp[it] = gc[(size_t)g2r * H_ + cc];
      int sp = sb[2048 + j20 + nn[it]];
      sx1[it] = *(const float4*)(symx + (size_t)sp * 512 + cc * 4);
    }
    #pragma unroll
    for (int nd = 0; nd < 2; ++nd) {
      int sp = sb[3072 + (j20 >> 1) + 2 * q + nd];
      sx2[nd] = *(const float4*)(symx + (size_t)sp * 512 + cc * 4);
    }
  }

  for (int k = 0; k < LVL23_CH; ++k) {
    const int tile = t0 + k;
    const int buf = k & 1;
    const bool hasNext = (k + 1 < LVL23_CH);

    *(int4*)&Ag[buf][rowA][coA] = agv;
    bar_lds();                        // Ag[buf] visible; also orders Bh/Bc reuse

    // next-tile index loads (L2-hot); value gathers issued mid-phase-1
    int gxr_n = 0, g2l_n[4], g2r_n[4], sp1_n[4], sp2_n[2];
    if (hasNext) {
      const int tn = tile + 1;
      const int* sbn = symbols + (size_t)(tn >> 6) * (N_ - 1);
      const int j2n = (tn & 63) * 16;
      gxr_n = idx1[tn * 32 + rowA];
      #pragma unroll
      for (int it = 0; it < 4; ++it) {
        g2l_n[it] = idx1[tn * 32 + 2 * nn[it]];
        g2r_n[it] = idx1[tn * 32 + 2 * nn[it] + 1];
        sp1_n[it] = sbn[2048 + j2n + nn[it]];
      }
      sp2_n[0] = sbn[3072 + (j2n >> 1) + 2 * q];
      sp2_n[1] = sbn[3072 + (j2n >> 1) + 2 * q + 1];
    }

    // ---- phase 1: 16 L2 nodes ----
    f32x4 acc[2][4];
    #pragma unroll
    for (int r = 0; r < 2; ++r)
      #pragma unroll
      for (int g = 0; g < 4; ++g) acc[r][g] = (f32x4){0.f, 0.f, 0.f, 0.f};
    #pragma unroll
    for (int K = 0; K < 4; ++K) {
      short8 a0 = *(const short8*)&Ag[buf][cL][K * 32 + q * 8];
      short8 a1 = *(const short8*)&Ag[buf][16 + cL][K * 32 + q * 8];
      #pragma unroll
      for (int g = 0; g < 4; ++g) {
        acc[0][g] = __builtin_amdgcn_mfma_f32_16x16x32_bf16(a0, bfr[g][K], acc[0][g], 0, 0, 0);
        acc[1][g] = __builtin_amdgcn_mfma_f32_16x16x32_bf16(a1, bfr[g][K], acc[1][g], 0, 0, 0);
      }
    }
    // issue next tile's long-latency gathers; they land during phase 2 /
    // next iteration (~2500 cy of cover).
    float clp_n[4], crp_n[4];
    float4 sx1_n[4], sx2_n[2];
    if (hasNext) {
      agv = *(const int4*)(gh8 + (size_t)gxr_n * H_ + coA);
      #pragma unroll
      for (int it = 0; it < 4; ++it) {
        clp_n[it] = gc[(size_t)g2l_n[it] * H_ + cc];
        crp_n[it] = gc[(size_t)g2r_n[it] * H_ + cc];
        sx1_n[it] = *(const float4*)(symx + (size_t)sp1_n[it] * 512 + cc * 4);
      }
      sx2_n[0] = *(const float4*)(symx + (size_t)sp2_n[0] * 512 + cc * 4);
      sx2_n[1] = *(const float4*)(symx + (size_t)sp2_n[1] * 512 + cc * 4);
    }

    #pragma unroll
    for (int r = 0; r < 2; ++r) {
      #pragma unroll
      for (int nd = 0; nd < 2; ++nd) {
        int it = r * 2 + nd;
        int n = 8 * r + 2 * q + nd;
        Gates gt = gate_combine(sx1[it],
            acc[r][0][2 * nd] + acc[r][0][2 * nd + 1],
            acc[r][1][2 * nd] + acc[r][1][2 * nd + 1],
            acc[r][2][2 * nd] + acc[r][2][2 * nd + 1],
            acc[r][3][2 * nd], acc[r][3][2 * nd + 1], clp[it], crp[it]);
        Bc[n][cc] = gt.cv;
        Bh[n][cc] = f2bf(gt.hv);
      }
    }
    bar_lds();                        // Bh/Bc visible

    // ---- phase 2: 8 L3 nodes ----
    f32x4 acc2[4];
    #pragma unroll
    for (int g = 0; g < 4; ++g) acc2[g] = (f32x4){0.f, 0.f, 0.f, 0.f};
    #pragma unroll
    for (int K = 0; K < 4; ++K) {
      short8 a0 = *(const short8*)&Bh[cL][K * 32 + q * 8];
      #pragma unroll
      for (int g = 0; g < 4; ++g)
        acc2[g] = __builtin_amdgcn_mfma_f32_16x16x32_bf16(a0, bfr[g][K], acc2[g], 0, 0, 0);
    }
    #pragma unroll
    for (int nd = 0; nd < 2; ++nd) {
      int n = 2 * q + nd;
      int G3 = tile * 8 + n;
      Gates gt = gate_combine(sx2[nd],
          acc2[0][2 * nd] + acc2[0][2 * nd + 1],
          acc2[1][2 * nd] + acc2[1][2 * nd + 1],
          acc2[2][2 * nd] + acc2[2][2 * nd + 1],
          acc2[3][2 * nd], acc2[3][2 * nd + 1],
          Bc[2 * n][cc], Bc[2 * n + 1][cc]);
      c_out[(size_t)G3 * H_ + cc] = gt.cv;
      h_out8[(size_t)G3 * H_ + cc] = f2bf(gt.hv);
    }
    // rotate prefetched values
    #pragma unroll
    for (int it = 0; it < 4; ++it) {
      clp[it] = clp_n[it]; crp[it] = crp_n[it]; sx1[it] = sx1_n[it];
    }
    sx2[0] = sx2_n[0]; sx2[1] = sx2_n[1];
  }
}

// ---- k_mid: levels 4-9 fused; 512 blocks, subtree-local, LDS ping-pong ----
// WEIGHT HOIST (fix for 1.8 GB of per-chunk Wfrag L2 re-reads: 16 short8/thread
// loaded once). NO launch_bounds min: hoist needs ~184 unified regs; the old
// (512,2) 128-reg cap would spill (r9 lesson). 1 block/CU, 2 grid passes.
__global__ void __launch_bounds__(512) k_mid(
    const unsigned short* __restrict__ Wfrag, const float* __restrict__ symx,
    const int* __restrict__ symbols,
    const unsigned short* __restrict__ in_h8, const float* __restrict__ in_c,
    unsigned short* __restrict__ out_h8, float* __restrict__ out_c) {
  __shared__ __align__(16) unsigned short Ah0[64][136];
  __shared__ __align__(16) unsigned short Ah1[32][136];
  __shared__ float Cs0[64][128];
  __shared__ float Cs1[32][128];
  int t = threadIdx.x;
  int w = t >> 6, L = t & 63, q = L >> 4, cL = L & 15;
  int cc = 16 * w + cL;
  int blk = blockIdx.x;
  int b = blk >> 3, sub = blk & 7;
  size_t base3 = (size_t)blk * 64;

  const short8* wf = (const short8*)Wfrag;
  short8 bfr[4][4];
  #pragma unroll
  for (int K = 0; K < 4; ++K)
    #pragma unroll
    for (int g = 0; g < 4; ++g)
      bfr[g][K] = wf[(size_t)((w + 8 * g) * 4 + K) * 64 + L];

  #pragma unroll
  for (int i = 0; i < 2; ++i) {
    int fid = t + 512 * i;
    int row = fid >> 4, co = (fid & 15) * 8;
    *(int4*)&Ah0[row][co] = *(const int4*)(in_h8 + (base3 + row) * H_ + co);
  }
  #pragma unroll
  for (int i = 0; i < 4; ++i) {
    int fid = t + 512 * i;
    int row = fid >> 5, c4 = (fid & 31) << 2;
    *(float4*)&Cs0[row][c4] = *(const float4*)(in_c + (base3 + row) * H_ + c4);
  }
  __syncthreads();

  int R = 64;
  #pragma unroll
  for (int lev = 0; lev < 6; ++lev) {
    const int l = 4 + lev;
    const int nodes = R >> 1;
    const int jb = b * (N_ - 1) + (N_ - (N_ >> (l - 1))) + ((sub * 32) >> lev);
    unsigned short (*Ard)[136] = (lev & 1) ? Ah1 : Ah0;
    unsigned short (*Awr)[136] = (lev & 1) ? Ah0 : Ah1;
    const float* crd = (lev & 1) ? &Cs1[0][0] : &Cs0[0][0];
    float* cwr = (lev & 1) ? &Cs0[0][0] : &Cs1[0][0];
    const int nchunk = (nodes + 15) >> 4;
    for (int c = 0; c < nchunk; ++c) {
      int spre[4];
      #pragma unroll
      for (int it = 0; it < 4; ++it) {
        int n = 16 * c + 8 * (it >> 1) + 2 * q + (it & 1);
        spre[it] = (n < nodes) ? symbols[jb + n] : 0;
      }
      f32x4 acc[2][4];
      #pragma unroll
      for (int r = 0; r < 2; ++r)
        #pragma unroll
        for (int g = 0; g < 4; ++g) acc[r][g] = (f32x4){0.f, 0.f, 0.f, 0.f};
      const bool useA1 = (2 * nodes - 32 * c) > 16;
      #pragma unroll
      for (int K = 0; K < 4; ++K) {
        short8 a0 = *(const short8*)&Ard[32 * c + cL][K * 32 + q * 8];
        #pragma unroll
        for (int g = 0; g < 4; ++g)
          acc[0][g] = __builtin_amdgcn_mfma_f32_16x16x32_bf16(a0, bfr[g][K], acc[0][g], 0, 0, 0);
        if (useA1) {
          short8 a1 = *(const short8*)&Ard[32 * c + 16 + cL][K * 32 + q * 8];
          #pragma unroll
          for (int g = 0; g < 4; ++g)
            acc[1][g] = __builtin_amdgcn_mfma_f32_16x16x32_bf16(a1, bfr[g][K], acc[1][g], 0, 0, 0);
        }
      }
      #pragma unroll
      for (int r = 0; r < 2; ++r) {
        #pragma unroll
        for (int nd = 0; nd < 2; ++nd) {
          int it = r * 2 + nd;
          int n = 16 * c + 8 * r + 2 * q + nd;
          if (n < nodes) {
            float4 sx = *(const float4*)(symx + (size_t)spre[it] * 512 + cc * 4);
            Gates gt = gate_combine(sx,
                acc[r][0][2 * nd] + acc[r][0][2 * nd + 1],
                acc[r][1][2 * nd] + acc[r][1][2 * nd + 1],
                acc[r][2][2 * nd] + acc[r][2][2 * nd + 1],
                acc[r][3][2 * nd], acc[r][3][2 * nd + 1],
                crd[(size_t)(2 * n) * 128 + cc], crd[(size_t)(2 * n + 1) * 128 + cc]);
            if (lev == 5) {
              out_c[(size_t)blk * H_ + cc] = gt.cv;
              out_h8[(size_t)blk * H_ + cc] = f2bf(gt.hv);
            } else {
              cwr[(size_t)n * 128 + cc] = gt.cv;
              Awr[n][cc] = f2bf(gt.hv);
            }
          }
        }
      }
    }
    __syncthreads();
    R >>= 1;
  }
}

// ---- k_fin: levels 10-12 + fused projection (direct Wout rows); 64 blocks ----
__global__ void __launch_bounds__(512, 2) k_fin(
    const unsigned short* __restrict__ Wfrag, const float* __restrict__ symx,
    const int* __restrict__ symbols,
    const unsigned short* __restrict__ in_h8, const float* __restrict__ in_c,
    const float* __restrict__ Wout, const float* __restrict__ bout,
    float* __restrict__ out) {
  __shared__ __align__(16) unsigned short Ah0[8][136];
  __shared__ __align__(16) unsigned short Ah1[4][136];
  __shared__ float Cs0[8][128];
  __shared__ float Cs1[4][128];
  __shared__ float rootv[128];
  int t = threadIdx.x;
  int w = t >> 6, L = t & 63, q = L >> 4, cL = L & 15;
  int cc = 16 * w + cL;
  int b = blockIdx.x;

  if (t < 128) {
    int row = t >> 4, co = (t & 15) * 8;
    *(int4*)&Ah0[row][co] = *(const int4*)(in_h8 + (size_t)(b * 8 + row) * H_ + co);
  }
  if (t < 256) {
    int row = t >> 5, c4 = (t & 31) << 2;
    *(float4*)&Cs0[row][c4] = *(const float4*)(in_c + (size_t)(b * 8 + row) * H_ + c4);
  }
  __syncthreads();

  const short8* wf = (const short8*)Wfrag;
  int R = 8;
  #pragma unroll
  for (int lev = 0; lev < 3; ++lev) {
    const int l = 10 + lev;
    const int nodes = R >> 1;
    const int jb = b * (N_ - 1) + (N_ - (N_ >> (l - 1)));
    unsigned short (*Ard)[136] = (lev & 1) ? Ah1 : Ah0;
    unsigned short (*Awr)[136] = (lev & 1) ? Ah0 : Ah1;
    const float* crd = (lev & 1) ? &Cs1[0][0] : &Cs0[0][0];
    float* cwr = (lev & 1) ? &Cs0[0][0] : &Cs1[0][0];
    int spre[4];
    #pragma unroll
    for (int it = 0; it < 4; ++it) {
      int n = 8 * (it >> 1) + 2 * q + (it & 1);
      spre[it] = (n < nodes) ? symbols[jb + n] : 0;
    }
    f32x4 acc[4];
    #pragma unroll
    for (int g = 0; g < 4; ++g) acc[g] = (f32x4){0.f, 0.f, 0.f, 0.f};
    #pragma unroll
    for (int K = 0; K < 4; ++K) {
      short8 bfr[4];
      #pragma unroll
      for (int g = 0; g < 4; ++g) bfr[g] = wf[(size_t)((w + 8 * g) * 4 + K) * 64 + L];
      short8 a0 = *(const short8*)&Ard[cL & 7][K * 32 + q * 8];
      #pragma unroll
      for (int g = 0; g < 4; ++g)
        acc[g] = __builtin_amdgcn_mfma_f32_16x16x32_bf16(a0, bfr[g], acc[g], 0, 0, 0);
    }
    #pragma unroll
    for (int nd = 0; nd < 2; ++nd) {
      int it = nd;
      int n = 2 * q + nd;
      if (n < nodes) {
        float4 sx = *(const float4*)(symx + (size_t)spre[it] * 512 + cc * 4);
        Gates gt = gate_combine(sx,
            acc[0][2 * nd] + acc[0][2 * nd + 1],
            acc[1][2 * nd] + acc[1][2 * nd + 1],
            acc[2][2 * nd] + acc[2][2 * nd + 1],
            acc[3][2 * nd], acc[3][2 * nd + 1],
            crd[(size_t)(2 * n) * 128 + cc], crd[(size_t)(2 * n + 1) * 128 + cc]);
        if (lev == 2) {
          rootv[cc] = gt.hv;
        } else {
          cwr[(size_t)n * 128 + cc] = gt.cv;
          Awr[n][cc] = f2bf(gt.hv);
        }
      }
    }
    __syncthreads();
    R >>= 1;
  }
  if (t < 128) {
    float acc = bout[t];
    const float4* wr = (const float4*)(Wout + t * H_);
    #pragma unroll 4
    for (int k4 = 0; k4 < H_ / 4; ++k4) {
      float4 w4 = wr[k4];
      acc = fmaf(rootv[4 * k4], w4.x, acc); acc = fmaf(rootv[4 * k4 + 1], w4.y, acc);
      acc = fmaf(rootv[4 * k4 + 2], w4.z, acc); acc = fmaf(rootv[4 * k4 + 3], w4.w, acc);
    }
    out[(size_t)b * H_ + t] = acc;
  }
}

extern "C" void kernel_launch(void* const* d_in, const int* in_sizes, int n_in,
                              void* d_out, int out_size, void* d_ws, size_t ws_size,
                              hipStream_t stream) {
  const int* tokens    = (const int*)d_in[0];
  const int* symbols   = (const int*)d_in[1];
  const float* emb     = (const float*)d_in[2];
  const float* sym_emb = (const float*)d_in[3];
  const float* Wp  = (const float*)d_in[4];
  const float* bp  = (const float*)d_in[5];
  const float* Wi  = (const float*)d_in[6];
  const float* bi  = (const float*)d_in[7];
  const float* Ui  = (const float*)d_in[8];
  const float* Wf  = (const float*)d_in[9];
  const float* bf  = (const float*)d_in[10];
  const float* Uf  = (const float*)d_in[11];
  const float* Wo  = (const float*)d_in[12];
  const float* bo  = (const float*)d_in[13];
  const float* Uo  = (const float*)d_in[14];
  const float* Wu  = (const float*)d_in[15];
  const float* bu  = (const float*)d_in[16];
  const float* Uu  = (const float*)d_in[17];
  const float* Wout= (const float*)d_in[18];
  const float* bout= (const float*)d_in[19];

  // Workspace layout
  char* ws = (char*)d_ws;
  unsigned short* Wfrag   = (unsigned short*)(ws);                  // 131072
  float*          leaf_c  = (float*)(ws + 759040);                  // 10752
  float*          symx    = (float*)(ws + 769792);                  // 102400
  float*          P_leaf  = (float*)(ws + 872192);                  // 43008
  unsigned short* tab_h8  = (unsigned short*)(ws + 2001152UL);      // 5644800
  float*          tab_c   = (float*)(ws + 7645952UL);               // 11289600
  int*            idx1    = (int*)(ws + 18935552UL);                // 524288
  unsigned short* L3h8    = (unsigned short*)(ws + 19459840UL);     // 8388608
  float*          L3c     = (float*)(ws + 27848448UL);              // 16777216
  unsigned short* L9h8    = (unsigned short*)(ws + 44625664UL);     // 131072
  float*          L9c     = (float*)(ws + 44756736UL);              // 262144

  k_pre<<<16 + V_ + S_ + 256, 512, 0, stream>>>(
      Ui, Uo, Uu, Uf, Wi, Wo, Wu, Wf, Wp, emb, sym_emb,
      bp, bi, bo, bu, bf, tokens, symbols,
      Wfrag, leaf_c, symx, P_leaf, idx1);
  k_tabB<<<NTAB / 2, 256, 0, stream>>>(P_leaf, symx, leaf_c, tab_h8, tab_c);
  k_lvl23<<<256, 512, 0, stream>>>(Wfrag, symx, symbols, idx1, tab_h8, tab_c,
                                   L3h8, L3c);
  k_mid<<<512, 512, 0, stream>>>(Wfrag, symx, symbols, L3h8, L3c, L9h8, L9c);
  k_fin<<<B_, 512, 0, stream>>>(Wfrag, symx, symbols, L9h8, L9c, Wout, bout,
                                (float*)d_out);
}